// Round 10
// baseline (207.327 us; speedup 1.0000x reference)
//
#include <hip/hip_runtime.h>
#include <hip/hip_bf16.h>

typedef unsigned short u16;
typedef unsigned int u32;
typedef __attribute__((ext_vector_type(8))) short short8;
typedef __attribute__((ext_vector_type(4))) short short4v;
typedef __attribute__((ext_vector_type(4))) float f32x4;

static __device__ __forceinline__ u16 f2bf(float f) {
    union { float f; unsigned u; } a; a.f = f;
    unsigned u = a.u;
    u += 0x7FFFu + ((u >> 16) & 1u);   // RNE; inputs are finite
    return (u16)(u >> 16);
}
static __device__ __forceinline__ float bf2f(u16 h) {
    union { u32 u; float f; } a; a.u = ((u32)h) << 16; return a.f;
}
static __device__ __forceinline__ u32 cvtpk(float lo, float hi) {   // [bf16(hi)<<16 | bf16(lo)]
    u32 r; asm("v_cvt_pk_bf16_f32 %0, %1, %2" : "=v"(r) : "v"(lo), "v"(hi)); return r;
}
static __device__ __forceinline__ void gload16(const u16* g, u16* l) {
    __builtin_amdgcn_global_load_lds((const __attribute__((address_space(1))) u32*)(const void*)g,
                                     (__attribute__((address_space(3))) u32*)(void*)l, 16, 0, 0);
}

// ---------------- Kernel 1: GroupNorm stats (blocks 0-31) + weight fp32->bf16 (blocks 32-287) ----
__global__ __launch_bounds__(256) void k_pre(const float* __restrict__ x, float* __restrict__ stats,
                                             const float* __restrict__ qw, const float* __restrict__ pw,
                                             u16* __restrict__ q2, u16* __restrict__ p2) {
    const int t = threadIdx.x;
    if (blockIdx.x >= 32) {
        const int i = ((int)blockIdx.x - 32) * 1024 + t * 4;
        const float* src; u16* dst;
        if (i < 196608) { src = qw + i; dst = q2 + i; }
        else            { src = pw + (i - 196608); dst = p2 + (i - 196608); }
        float4 v = *reinterpret_cast<const float4*>(src);
        u16 o[4] = { f2bf(v.x), f2bf(v.y), f2bf(v.z), f2bf(v.w) };
        *reinterpret_cast<uint2*>(dst) = *reinterpret_cast<uint2*>(o);
        return;
    }
    const int bg = blockIdx.x;
    const float* p = x + (size_t)bg * (32 * 4096);
    float s = 0.f, ss = 0.f;
    for (int i = t * 4; i < 32 * 4096; i += 256 * 4) {
        float4 v = *reinterpret_cast<const float4*>(p + i);
        s  += v.x + v.y + v.z + v.w;
        ss += v.x * v.x + v.y * v.y + v.z * v.z + v.w * v.w;
    }
    for (int off = 1; off < 64; off <<= 1) { s += __shfl_xor(s, off); ss += __shfl_xor(ss, off); }
    __shared__ float ls[4], lss[4];
    if ((t & 63) == 0) { ls[t >> 6] = s; lss[t >> 6] = ss; }
    __syncthreads();
    if (t == 0) {
        float S  = ls[0] + ls[1] + ls[2] + ls[3];
        float SS = lss[0] + lss[1] + lss[2] + lss[3];
        const float inv = 1.f / (32.f * 4096.f);
        float mu  = S * inv;
        float var = SS * inv - mu * mu;
        stats[bg * 2]     = mu;
        stats[bg * 2 + 1] = rsqrtf(var + 1e-5f);
    }
}

// ---------------- Kernel 1c: GN-normalize + transpose -> Hbf (B,N,C) bf16 ----------------
__global__ __launch_bounds__(256) void k_norm(const float* __restrict__ x, const float* __restrict__ gamma,
                                              const float* __restrict__ beta, const float* __restrict__ stats,
                                              u16* __restrict__ H) {
    __shared__ u16 T[64][72];   // [c_local][n_local]
    const int b = blockIdx.z, c0 = blockIdx.y * 64, n0 = blockIdx.x * 64;
    const int t = threadIdx.x;
    const int cl = t >> 2, nb = (t & 3) * 16;
    const int c = c0 + cl;
    const float mu = stats[(b * 8 + (c >> 5)) * 2];
    const float rstd = stats[(b * 8 + (c >> 5)) * 2 + 1];
    const float ga = gamma[c] * rstd, be = beta[c] - mu * ga;
    const float* xp = &x[((size_t)b * 256 + c) * 4096 + n0 + nb];
#pragma unroll
    for (int j = 0; j < 16; j += 4) {
        float4 v = *reinterpret_cast<const float4*>(xp + j);
        T[cl][nb + j + 0] = f2bf(v.x * ga + be);
        T[cl][nb + j + 1] = f2bf(v.y * ga + be);
        T[cl][nb + j + 2] = f2bf(v.z * ga + be);
        T[cl][nb + j + 3] = f2bf(v.w * ga + be);
    }
    __syncthreads();
    const int nl = t >> 2, cb = (t & 3) * 16;
    short8 s0, s1;
#pragma unroll
    for (int j = 0; j < 8; ++j) { s0[j] = (short)T[cb + j][nl]; s1[j] = (short)T[cb + 8 + j][nl]; }
    u16* dst = &H[((size_t)b * 4096 + n0 + nl) * 256 + c0 + cb];
    *reinterpret_cast<short8*>(dst)     = s0;
    *reinterpret_cast<short8*>(dst + 8) = s1;
}

// ---------------- Kernel 2: QKV as bf16 MFMA GEMM ----------------
// Writes: Q (B,N,C) scaled by 1/16*log2(e) ; K (B,N,C) ; V (B,C,N) with per-32-key-block
// XOR-swizzle: key-group g (4 keys) stored at slot g ^ ((ch>>1)&7).
__global__ __launch_bounds__(256) void k_qkv(const u16* __restrict__ H, const u16* __restrict__ W2,
                                             const float* __restrict__ qkv_b,
                                             u16* __restrict__ Q, u16* __restrict__ K, u16* __restrict__ V) {
    __shared__ u16 T[9216];   // Q/K: [128][72] ; V: [64][144]
    const int b = blockIdx.z, o0 = blockIdx.x * 64, nb0 = blockIdx.y * 128;
    const int t = threadIdx.x, w = t >> 6, l = t & 63, lr = l & 15, lg = l >> 4;
    const size_t bN = (size_t)b * 4096;
    f32x4 acc[2][4];
#pragma unroll
    for (int m = 0; m < 2; ++m)
#pragma unroll
        for (int nf = 0; nf < 4; ++nf) acc[m][nf] = f32x4{0.f, 0.f, 0.f, 0.f};
    const u16* A0 = &H[(bN + nb0 + w * 32 + lr) * 256];
    const u16* A1 = A0 + 16 * 256;
#pragma unroll
    for (int cc = 0; cc < 8; ++cc) {
        short8 af0 = *reinterpret_cast<const short8*>(A0 + cc * 32 + lg * 8);
        short8 af1 = *reinterpret_cast<const short8*>(A1 + cc * 32 + lg * 8);
#pragma unroll
        for (int nf = 0; nf < 4; ++nf) {
            short8 bf = *reinterpret_cast<const short8*>(&W2[(size_t)(o0 + nf * 16 + lr) * 256 + cc * 32 + lg * 8]);
            acc[0][nf] = __builtin_amdgcn_mfma_f32_16x16x32_bf16(af0, bf, acc[0][nf], 0, 0, 0);
            acc[1][nf] = __builtin_amdgcn_mfma_f32_16x16x32_bf16(af1, bf, acc[1][nf], 0, 0, 0);
        }
    }
    const int og = o0 >> 8;   // 0=Q, 1=K, 2=V
    const float scal = (og == 0) ? 0.0625f * 1.44269504f : 1.0f;   // fold C^-0.5 * log2(e) into Q
    float bias[4];
#pragma unroll
    for (int nf = 0; nf < 4; ++nf) bias[nf] = qkv_b[o0 + nf * 16 + lr];
    if (og < 2) {
#pragma unroll
        for (int m = 0; m < 2; ++m)
#pragma unroll
            for (int nf = 0; nf < 4; ++nf)
#pragma unroll
                for (int i = 0; i < 4; ++i)
                    T[(w * 32 + m * 16 + lg * 4 + i) * 72 + nf * 16 + lr] = f2bf((acc[m][nf][i] + bias[nf]) * scal);
        __syncthreads();
        const int rl = t >> 1, half = (t & 1) * 32;
        u16* dst = (og == 0 ? Q : K) + (bN + nb0 + rl) * 256 + (o0 & 255) + half;
#pragma unroll
        for (int j = 0; j < 4; ++j)
            *reinterpret_cast<short8*>(dst + j * 8) = *reinterpret_cast<short8*>(&T[rl * 72 + half + j * 8]);
    } else {
#pragma unroll
        for (int m = 0; m < 2; ++m)
#pragma unroll
            for (int nf = 0; nf < 4; ++nf)
#pragma unroll
                for (int i = 0; i < 4; ++i)
                    T[(nf * 16 + lr) * 144 + w * 32 + m * 16 + lg * 4 + i] = f2bf(acc[m][nf][i] + bias[nf]);
        __syncthreads();
        const int ol = t >> 2, nbl = (t & 3) * 32;
        const int s_ = (ol >> 1) & 7;                    // == (global_ch>>1)&7 since o0%64==0
        u16* dst = V + ((size_t)b * 256 + (o0 - 512) + ol) * 4096 + nb0 + nbl;
#pragma unroll
        for (int j = 0; j < 4; ++j) {
            short8 vv = *reinterpret_cast<short8*>(&T[ol * 144 + nbl + j * 8]);
            short8 ov;
            if (s_ & 1) ov = short8{vv[4], vv[5], vv[6], vv[7], vv[0], vv[1], vv[2], vv[3]};
            else        ov = vv;
            *reinterpret_cast<short8*>(dst + (((2 * j) ^ (s_ & 6)) * 4)) = ov;
        }
    }
}

// ---------------- Kernel 3: flash attention, 64-key staging, V in two 32-key halves ----------------
// Grid (4 sp, 4 b, 16 qtiles): XCD-local K/V slices. Block = 512 thr = 8 waves, wave owns 32 q.
__global__ __launch_bounds__(512, 1) void k_flash(const u16* __restrict__ Qw, const u16* __restrict__ Kw,
                                                  const u16* __restrict__ Vw, u16* __restrict__ Opart,
                                                  float* __restrict__ ml) {
    __shared__ u16 Ks[2][16384];    // [64 keys][256 ch], 16B-granule XOR(row&7) swizzle
    __shared__ u16 Vs[2][16384];    // two halves: [st][256 ch][32 keys], slot-swizzled
    const int sp = blockIdx.x, b = blockIdx.y;
    const int tid = threadIdx.x;
    const int w = tid >> 6, l = tid & 63;
    const int lr = l & 15, lg = l >> 4;
    const int qbase = blockIdx.z * 256 + w * 32;
    const int kb0 = sp * 1024;
    const size_t bN = (size_t)b * 4096;

    const u16* srcK = Kw + (bN + kb0 + (tid >> 5)) * 256 + (((tid & 31) * 8) ^ (((tid >> 5) & 7) * 8));
    const int u = tid & 255, sth = tid >> 8;   // V: 256-thread group per 32-key half
    const u16* srcV = Vw + ((size_t)b * 256 + (u >> 2)) * 4096 + kb0 + sth * 32 + (u & 3) * 8;
    const int vdst = sth * 8192 + u * 8;       // wave-uniform base + lane*8

#define STAGE(d, toff) { \
        const u16* sk_ = srcK + (size_t)(toff) * 16384; \
        const u16* sv_ = srcV + (toff) * 64; \
        gload16(sk_,               Ks[d] + tid * 8); \
        gload16(sk_ + 16 * 256,    Ks[d] + 4096 + tid * 8); \
        gload16(sk_ + 32 * 256,    Ks[d] + 8192 + tid * 8); \
        gload16(sk_ + 48 * 256,    Ks[d] + 12288 + tid * 8); \
        gload16(sv_,               Vs[d] + vdst); \
        gload16(sv_ + 64 * 4096,   Vs[d] + vdst + 2048); \
        gload16(sv_ + 128 * 4096,  Vs[d] + vdst + 4096); \
        gload16(sv_ + 192 * 4096,  Vs[d] + vdst + 6144); }

    const int c6 = (lr >> 2) & 1;
    int kofs[2];
#pragma unroll
    for (int n = 0; n < 2; ++n) kofs[n] = (n * 16 + lr) * 256 + ((lg * 8) ^ ((lr & 3) * 8));
    const int vslotA = ((lg ^ (lr >> 1)) * 4);   // r4-verified slot math (32-key rows)
    const int vslotB = vslotA ^ 16;

    short8 qf[2][8];
#pragma unroll
    for (int m = 0; m < 2; ++m)
#pragma unroll
        for (int cc = 0; cc < 8; ++cc)
            qf[m][cc] = *reinterpret_cast<const short8*>(&Qw[(bN + qbase + m * 16 + lr) * 256 + cc * 32 + lg * 8]);

    f32x4 Oa[2][16];
    float mr[2], lsum[2];
#pragma unroll
    for (int m = 0; m < 2; ++m) {
#pragma unroll
        for (int cs = 0; cs < 16; ++cs) Oa[m][cs] = f32x4{0.f, 0.f, 0.f, 0.f};
        mr[m] = -1e30f; lsum[m] = 0.f;
    }

    STAGE(0, 0);
    for (int kt = 0; kt < 16; ++kt) {
        const int d = kt & 1;
        asm volatile("s_waitcnt vmcnt(0)" ::: "memory");
        __builtin_amdgcn_sched_barrier(0);
        __builtin_amdgcn_s_barrier();
        if (kt < 15) STAGE(d ^ 1, kt + 1);

#pragma unroll
        for (int st = 0; st < 2; ++st) {
            const int kO = st * 8192;
            const int vH = st * 8192;           // V half base (u16)
            f32x4 sc[2][2];
#pragma unroll
            for (int m = 0; m < 2; ++m)
#pragma unroll
                for (int n = 0; n < 2; ++n) sc[m][n] = f32x4{0.f, 0.f, 0.f, 0.f};
            __builtin_amdgcn_s_setprio(1);
#pragma unroll
            for (int cc = 0; cc < 8; ++cc) {
                const int cb = ((cc ^ c6) << 5);
                short8 kf0 = *reinterpret_cast<const short8*>(&Ks[d][kO + kofs[0] + cb]);
                short8 kf1 = *reinterpret_cast<const short8*>(&Ks[d][kO + kofs[1] + cb]);
                sc[0][0] = __builtin_amdgcn_mfma_f32_16x16x32_bf16(kf0, qf[0][cc], sc[0][0], 0, 0, 0);
                sc[0][1] = __builtin_amdgcn_mfma_f32_16x16x32_bf16(kf1, qf[0][cc], sc[0][1], 0, 0, 0);
                sc[1][0] = __builtin_amdgcn_mfma_f32_16x16x32_bf16(kf0, qf[1][cc], sc[1][0], 0, 0, 0);
                sc[1][1] = __builtin_amdgcn_mfma_f32_16x16x32_bf16(kf1, qf[1][cc], sc[1][1], 0, 0, 0);
            }
            __builtin_amdgcn_s_setprio(0);

            float tmax[2];
            bool need = false;
#pragma unroll
            for (int m = 0; m < 2; ++m) {
                float tm = fmaxf(fmaxf(fmaxf(sc[m][0][0], sc[m][0][1]), fmaxf(sc[m][0][2], sc[m][0][3])),
                                 fmaxf(fmaxf(sc[m][1][0], sc[m][1][1]), fmaxf(sc[m][1][2], sc[m][1][3])));
                tm = fmaxf(tm, __shfl_xor(tm, 16));
                tm = fmaxf(tm, __shfl_xor(tm, 32));
                tmax[m] = tm;
                need = need || (tm > mr[m] + 8.f);
            }
            if (__any(need)) {   // defer-max (T13)
                float av[2][4];
#pragma unroll
                for (int m = 0; m < 2; ++m) {
                    float mn = fmaxf(mr[m], tmax[m]);
                    float al = exp2f(mr[m] - mn);
                    mr[m] = mn;
                    lsum[m] *= al;
#pragma unroll
                    for (int i = 0; i < 4; ++i) av[m][i] = __shfl(al, lg * 4 + i);
                }
#pragma unroll
                for (int m = 0; m < 2; ++m)
#pragma unroll
                    for (int cs = 0; cs < 16; ++cs)
#pragma unroll
                        for (int i = 0; i < 4; ++i) Oa[m][cs][i] *= av[m][i];
            }
            union { u32 uw[4]; short8 v; } pf[2];
#pragma unroll
            for (int m = 0; m < 2; ++m) {
                float p[8];
                float la = 0.f;
#pragma unroll
                for (int n = 0; n < 2; ++n)
#pragma unroll
                    for (int i = 0; i < 4; ++i) {
                        float pv = exp2f(sc[m][n][i] - mr[m]);
                        la += pv;
                        p[n * 4 + i] = pv;
                    }
                lsum[m] += la;
#pragma unroll
                for (int j = 0; j < 4; ++j) pf[m].uw[j] = cvtpk(p[2 * j], p[2 * j + 1]);
            }
            __builtin_amdgcn_s_setprio(1);
#pragma unroll
            for (int cs = 0; cs < 16; ++cs) {
                const int base = vH + (cs * 16 + lr) * 32;
                short4v lo = *reinterpret_cast<const short4v*>(&Vs[d][base + vslotA]);
                short4v hi = *reinterpret_cast<const short4v*>(&Vs[d][base + vslotB]);
                short8 vf = __builtin_shufflevector(lo, hi, 0, 1, 2, 3, 4, 5, 6, 7);
                Oa[0][cs] = __builtin_amdgcn_mfma_f32_16x16x32_bf16(pf[0].v, vf, Oa[0][cs], 0, 0, 0);
                Oa[1][cs] = __builtin_amdgcn_mfma_f32_16x16x32_bf16(pf[1].v, vf, Oa[1][cs], 0, 0, 0);
            }
            __builtin_amdgcn_s_setprio(0);
        }
    }
#undef STAGE

    float lt[2];
#pragma unroll
    for (int m = 0; m < 2; ++m) {
        float ts = lsum[m];
        ts += __shfl_xor(ts, 16);
        ts += __shfl_xor(ts, 32);
        lt[m] = ts;
    }
    const size_t obase = ((size_t)(b * 4 + sp) * 4096 + qbase);
#pragma unroll
    for (int m = 0; m < 2; ++m)
#pragma unroll
        for (int cs = 0; cs < 16; ++cs)
#pragma unroll
            for (int i = 0; i < 4; ++i)
                Opart[(obase + m * 16 + lg * 4 + i) * 256 + cs * 16 + lr] = f2bf(Oa[m][cs][i]);
    if (lg == 0) {
#pragma unroll
        for (int m = 0; m < 2; ++m) {
            size_t r = obase + m * 16 + lr;
            ml[r * 2]     = mr[m];
            ml[r * 2 + 1] = lt[m];
        }
    }
}

// ---------------- Kernel 4: fused split-combine + proj GEMM + bias + residual ----------------
// Combines the 4 split-KV partials in registers at A-fragment load time (replaces k_comb).
__global__ __launch_bounds__(256) void k_proj(const u16* __restrict__ Opart, const float* __restrict__ ml,
                                              const u16* __restrict__ Wp, const float* __restrict__ proj_b,
                                              const float* __restrict__ x, float* __restrict__ out) {
    __shared__ float T[64][132];   // [c_local][n_local] f32
    const int b = blockIdx.z, c0 = blockIdx.x * 64, nb0 = blockIdx.y * 128;
    const int t = threadIdx.x, w = t >> 6, l = t & 63, lr = l & 15, lg = l >> 4;
    const size_t base0 = (size_t)(b * 4) * 4096;          // Opart row base (split 0)
    const int r0 = nb0 + w * 32 + lr;                     // this lane's A rows: r0, r0+16

    // per-row softmax-combine weights (normalized)
    float Wc[2][4];
#pragma unroll
    for (int m = 0; m < 2; ++m) {
        const int rr = r0 + m * 16;
        float ms[4], lsv[4];
#pragma unroll
        for (int s = 0; s < 4; ++s) {
            const float* mp = &ml[(base0 + (size_t)s * 4096 + rr) * 2];
            ms[s] = mp[0]; lsv[s] = mp[1];
        }
        float M = fmaxf(fmaxf(ms[0], ms[1]), fmaxf(ms[2], ms[3]));
        float L = 0.f;
#pragma unroll
        for (int s = 0; s < 4; ++s) { Wc[m][s] = exp2f(ms[s] - M); L += Wc[m][s] * lsv[s]; }
        const float inv = 1.f / L;
#pragma unroll
        for (int s = 0; s < 4; ++s) Wc[m][s] *= inv;
    }

    f32x4 acc[2][4];
#pragma unroll
    for (int m = 0; m < 2; ++m)
#pragma unroll
        for (int nf = 0; nf < 4; ++nf) acc[m][nf] = f32x4{0.f, 0.f, 0.f, 0.f};

    const u16* Ap0 = &Opart[(base0 + r0) * 256];
    const u16* Ap1 = Ap0 + 16 * 256;
#pragma unroll
    for (int cc = 0; cc < 8; ++cc) {
        short8 af[2];
#pragma unroll
        for (int m = 0; m < 2; ++m) {
            const u16* ap = (m == 0 ? Ap0 : Ap1) + cc * 32 + lg * 8;
            short8 v0 = *reinterpret_cast<const short8*>(ap);
            short8 v1 = *reinterpret_cast<const short8*>(ap + 1048576);    // +1*4096*256
            short8 v2 = *reinterpret_cast<const short8*>(ap + 2097152);
            short8 v3 = *reinterpret_cast<const short8*>(ap + 3145728);
            union { u32 uw[4]; short8 v; } pk;
#pragma unroll
            for (int j = 0; j < 4; ++j) {
                float a = Wc[m][0] * bf2f((u16)v0[2 * j])     + Wc[m][1] * bf2f((u16)v1[2 * j])
                        + Wc[m][2] * bf2f((u16)v2[2 * j])     + Wc[m][3] * bf2f((u16)v3[2 * j]);
                float bb = Wc[m][0] * bf2f((u16)v0[2 * j + 1]) + Wc[m][1] * bf2f((u16)v1[2 * j + 1])
                         + Wc[m][2] * bf2f((u16)v2[2 * j + 1]) + Wc[m][3] * bf2f((u16)v3[2 * j + 1]);
                pk.uw[j] = cvtpk(a, bb);
            }
            af[m] = pk.v;
        }
#pragma unroll
        for (int nf = 0; nf < 4; ++nf) {
            short8 bf = *reinterpret_cast<const short8*>(&Wp[(size_t)(c0 + nf * 16 + lr) * 256 + cc * 32 + lg * 8]);
            acc[0][nf] = __builtin_amdgcn_mfma_f32_16x16x32_bf16(af[0], bf, acc[0][nf], 0, 0, 0);
            acc[1][nf] = __builtin_amdgcn_mfma_f32_16x16x32_bf16(af[1], bf, acc[1][nf], 0, 0, 0);
        }
    }
#pragma unroll
    for (int m = 0; m < 2; ++m)
#pragma unroll
        for (int nf = 0; nf < 4; ++nf)
#pragma unroll
            for (int i = 0; i < 4; ++i)
                T[nf * 16 + lr][w * 32 + m * 16 + lg * 4 + i] = acc[m][nf][i];
    __syncthreads();
    const int cl = t >> 2, nbl = (t & 3) * 32;
    const float pb = proj_b[c0 + cl];
    const size_t base = ((size_t)b * 256 + c0 + cl) * 4096 + nb0 + nbl;
#pragma unroll
    for (int j = 0; j < 32; j += 4) {
        float4 xv = *reinterpret_cast<const float4*>(&x[base + j]);
        float4 r;
        r.x = xv.x + T[cl][nbl + j + 0] + pb;
        r.y = xv.y + T[cl][nbl + j + 1] + pb;
        r.z = xv.z + T[cl][nbl + j + 2] + pb;
        r.w = xv.w + T[cl][nbl + j + 3] + pb;
        *reinterpret_cast<float4*>(&out[base + j]) = r;
    }
}

extern "C" void kernel_launch(void* const* d_in, const int* in_sizes, int n_in,
                              void* d_out, int out_size, void* d_ws, size_t ws_size,
                              hipStream_t stream) {
    const float* x      = (const float*)d_in[0];
    const float* gngam  = (const float*)d_in[1];
    const float* gnbeta = (const float*)d_in[2];
    const float* qkv_w  = (const float*)d_in[3];
    const float* qkv_b  = (const float*)d_in[4];
    const float* proj_w = (const float*)d_in[5];
    const float* proj_b = (const float*)d_in[6];
    float* out = (float*)d_out;

    char* wsb = (char*)d_ws;
    float* stats = (float*)wsb;                       // 1 KB
    u16* Hbf   = (u16*)(wsb + 1024);                  // 8 MB (B,N,C)
    u16* Qws   = Hbf + 4194304;                       // 8 MB (B,N,C) pre-scaled
    u16* Kws   = Qws + 4194304;                       // 8 MB (B,N,C)
    u16* Vws   = Kws + 4194304;                       // 8 MB (B,C,N) slot-swizzled
    u16* W2q   = Vws + 4194304;                       // 384 KB
    u16* W2p   = W2q + 196608;                        // 128 KB
    u16* Opart = W2p + 65536;                         // 32 MB (B,S,N,C) unnormalized
    float* ml  = (float*)(Opart + 16777216);          // 512 KB (B,S,N,2)

    k_pre<<<288, 256, 0, stream>>>(x, stats, qkv_w, proj_w, W2q, W2p);
    k_norm<<<dim3(64, 4, 4), 256, 0, stream>>>(x, gngam, gnbeta, stats, Hbf);
    k_qkv<<<dim3(12, 32, 4), 256, 0, stream>>>(Hbf, W2q, qkv_b, Qws, Kws, Vws);
    k_flash<<<dim3(4, 4, 16), 512, 0, stream>>>(Qws, Kws, Vws, Opart, ml);
    k_proj<<<dim3(4, 32, 4), 256, 0, stream>>>(Opart, ml, W2p, proj_b, x, out);
}

// Round 11
// 202.219 us; speedup vs baseline: 1.0253x; 1.0253x over previous
//
#include <hip/hip_runtime.h>
#include <hip/hip_bf16.h>

typedef unsigned short u16;
typedef unsigned int u32;
typedef __attribute__((ext_vector_type(8))) short short8;
typedef __attribute__((ext_vector_type(4))) short short4v;
typedef __attribute__((ext_vector_type(4))) float f32x4;

static __device__ __forceinline__ u16 f2bf(float f) {
    union { float f; unsigned u; } a; a.f = f;
    unsigned u = a.u;
    u += 0x7FFFu + ((u >> 16) & 1u);   // RNE; inputs are finite
    return (u16)(u >> 16);
}
static __device__ __forceinline__ float bf2f(u16 h) {
    union { u32 u; float f; } a; a.u = ((u32)h) << 16; return a.f;
}
static __device__ __forceinline__ u32 cvtpk(float lo, float hi) {   // [bf16(hi)<<16 | bf16(lo)]
    u32 r; asm("v_cvt_pk_bf16_f32 %0, %1, %2" : "=v"(r) : "v"(lo), "v"(hi)); return r;
}
static __device__ __forceinline__ void gload16(const u16* g, u16* l) {
    __builtin_amdgcn_global_load_lds((const __attribute__((address_space(1))) u32*)(const void*)g,
                                     (__attribute__((address_space(3))) u32*)(void*)l, 16, 0, 0);
}

// ---------------- Kernel 1: GroupNorm stats (blocks 0-31) + weight fp32->bf16 (blocks 32-287) ----
__global__ __launch_bounds__(256) void k_pre(const float* __restrict__ x, float* __restrict__ stats,
                                             const float* __restrict__ qw, const float* __restrict__ pw,
                                             u16* __restrict__ q2, u16* __restrict__ p2) {
    const int t = threadIdx.x;
    if (blockIdx.x >= 32) {
        const int i = ((int)blockIdx.x - 32) * 1024 + t * 4;
        const float* src; u16* dst;
        if (i < 196608) { src = qw + i; dst = q2 + i; }
        else            { src = pw + (i - 196608); dst = p2 + (i - 196608); }
        float4 v = *reinterpret_cast<const float4*>(src);
        u16 o[4] = { f2bf(v.x), f2bf(v.y), f2bf(v.z), f2bf(v.w) };
        *reinterpret_cast<uint2*>(dst) = *reinterpret_cast<uint2*>(o);
        return;
    }
    const int bg = blockIdx.x;
    const float* p = x + (size_t)bg * (32 * 4096);
    float s = 0.f, ss = 0.f;
    for (int i = t * 4; i < 32 * 4096; i += 256 * 4) {
        float4 v = *reinterpret_cast<const float4*>(p + i);
        s  += v.x + v.y + v.z + v.w;
        ss += v.x * v.x + v.y * v.y + v.z * v.z + v.w * v.w;
    }
    for (int off = 1; off < 64; off <<= 1) { s += __shfl_xor(s, off); ss += __shfl_xor(ss, off); }
    __shared__ float ls[4], lss[4];
    if ((t & 63) == 0) { ls[t >> 6] = s; lss[t >> 6] = ss; }
    __syncthreads();
    if (t == 0) {
        float S  = ls[0] + ls[1] + ls[2] + ls[3];
        float SS = lss[0] + lss[1] + lss[2] + lss[3];
        const float inv = 1.f / (32.f * 4096.f);
        float mu  = S * inv;
        float var = SS * inv - mu * mu;
        stats[bg * 2]     = mu;
        stats[bg * 2 + 1] = rsqrtf(var + 1e-5f);
    }
}

// ---------------- Kernel 1c: GN-normalize + transpose -> Hbf (B,N,C) bf16 ----------------
__global__ __launch_bounds__(256) void k_norm(const float* __restrict__ x, const float* __restrict__ gamma,
                                              const float* __restrict__ beta, const float* __restrict__ stats,
                                              u16* __restrict__ H) {
    __shared__ u16 T[64][72];   // [c_local][n_local]
    const int b = blockIdx.z, c0 = blockIdx.y * 64, n0 = blockIdx.x * 64;
    const int t = threadIdx.x;
    const int cl = t >> 2, nb = (t & 3) * 16;
    const int c = c0 + cl;
    const float mu = stats[(b * 8 + (c >> 5)) * 2];
    const float rstd = stats[(b * 8 + (c >> 5)) * 2 + 1];
    const float ga = gamma[c] * rstd, be = beta[c] - mu * ga;
    const float* xp = &x[((size_t)b * 256 + c) * 4096 + n0 + nb];
#pragma unroll
    for (int j = 0; j < 16; j += 4) {
        float4 v = *reinterpret_cast<const float4*>(xp + j);
        T[cl][nb + j + 0] = f2bf(v.x * ga + be);
        T[cl][nb + j + 1] = f2bf(v.y * ga + be);
        T[cl][nb + j + 2] = f2bf(v.z * ga + be);
        T[cl][nb + j + 3] = f2bf(v.w * ga + be);
    }
    __syncthreads();
    const int nl = t >> 2, cb = (t & 3) * 16;
    short8 s0, s1;
#pragma unroll
    for (int j = 0; j < 8; ++j) { s0[j] = (short)T[cb + j][nl]; s1[j] = (short)T[cb + 8 + j][nl]; }
    u16* dst = &H[((size_t)b * 4096 + n0 + nl) * 256 + c0 + cb];
    *reinterpret_cast<short8*>(dst)     = s0;
    *reinterpret_cast<short8*>(dst + 8) = s1;
}

// ---------------- Kernel 2: QKV as bf16 MFMA GEMM, 128n x 128o tiles ----------------
// A-fragments loaded once per cc serve 8 W-fragments (2x A-reuse vs 64-o tiles).
// Writes: Q (B,N,C) scaled by 1/16*log2(e) ; K (B,N,C) ; V (B,C,N) slot-swizzled.
__global__ __launch_bounds__(256) void k_qkv(const u16* __restrict__ H, const u16* __restrict__ W2,
                                             const float* __restrict__ qkv_b,
                                             u16* __restrict__ Q, u16* __restrict__ K, u16* __restrict__ V) {
    __shared__ u16 T[9216];   // Q/K: [128][72] ; V: [64][144]
    const int b = blockIdx.z, o0 = blockIdx.x * 128, nb0 = blockIdx.y * 128;
    const int t = threadIdx.x, w = t >> 6, l = t & 63, lr = l & 15, lg = l >> 4;
    const size_t bN = (size_t)b * 4096;
    f32x4 acc[2][8];
#pragma unroll
    for (int m = 0; m < 2; ++m)
#pragma unroll
        for (int nf = 0; nf < 8; ++nf) acc[m][nf] = f32x4{0.f, 0.f, 0.f, 0.f};
    const u16* A0 = &H[(bN + nb0 + w * 32 + lr) * 256];
    const u16* A1 = A0 + 16 * 256;
#pragma unroll
    for (int cc = 0; cc < 8; ++cc) {
        short8 af0 = *reinterpret_cast<const short8*>(A0 + cc * 32 + lg * 8);
        short8 af1 = *reinterpret_cast<const short8*>(A1 + cc * 32 + lg * 8);
#pragma unroll
        for (int nf = 0; nf < 8; ++nf) {
            short8 bf = *reinterpret_cast<const short8*>(&W2[(size_t)(o0 + nf * 16 + lr) * 256 + cc * 32 + lg * 8]);
            acc[0][nf] = __builtin_amdgcn_mfma_f32_16x16x32_bf16(af0, bf, acc[0][nf], 0, 0, 0);
            acc[1][nf] = __builtin_amdgcn_mfma_f32_16x16x32_bf16(af1, bf, acc[1][nf], 0, 0, 0);
        }
    }
    const int og = o0 >> 8;   // 0=Q (o0 in {0,128}), 1=K ({256,384}), 2=V ({512,640})
    const float scal = (og == 0) ? 0.0625f * 1.44269504f : 1.0f;   // fold C^-0.5 * log2(e) into Q
#pragma unroll
    for (int oh = 0; oh < 2; ++oh) {
        const int o0h = o0 + oh * 64;
        float bias[4];
#pragma unroll
        for (int nf = 0; nf < 4; ++nf) bias[nf] = qkv_b[o0h + nf * 16 + lr];
        if (og < 2) {
#pragma unroll
            for (int m = 0; m < 2; ++m)
#pragma unroll
                for (int nf = 0; nf < 4; ++nf)
#pragma unroll
                    for (int i = 0; i < 4; ++i)
                        T[(w * 32 + m * 16 + lg * 4 + i) * 72 + nf * 16 + lr] =
                            f2bf((acc[m][oh * 4 + nf][i] + bias[nf]) * scal);
            __syncthreads();
            const int rl = t >> 1, half = (t & 1) * 32;
            u16* dst = (og == 0 ? Q : K) + (bN + nb0 + rl) * 256 + (o0h & 255) + half;
#pragma unroll
            for (int j = 0; j < 4; ++j)
                *reinterpret_cast<short8*>(dst + j * 8) = *reinterpret_cast<short8*>(&T[rl * 72 + half + j * 8]);
            __syncthreads();
        } else {
#pragma unroll
            for (int m = 0; m < 2; ++m)
#pragma unroll
                for (int nf = 0; nf < 4; ++nf)
#pragma unroll
                    for (int i = 0; i < 4; ++i)
                        T[(nf * 16 + lr) * 144 + w * 32 + m * 16 + lg * 4 + i] =
                            f2bf(acc[m][oh * 4 + nf][i] + bias[nf]);
            __syncthreads();
            const int ol = t >> 2, nbl = (t & 3) * 32;
            const int s_ = (ol >> 1) & 7;                // == (global_ch>>1)&7 since o0h%64==0
            u16* dst = V + ((size_t)b * 256 + (o0h - 512) + ol) * 4096 + nb0 + nbl;
#pragma unroll
            for (int j = 0; j < 4; ++j) {
                short8 vv = *reinterpret_cast<short8*>(&T[ol * 144 + nbl + j * 8]);
                short8 ov;
                if (s_ & 1) ov = short8{vv[4], vv[5], vv[6], vv[7], vv[0], vv[1], vv[2], vv[3]};
                else        ov = vv;
                *reinterpret_cast<short8*>(dst + (((2 * j) ^ (s_ & 6)) * 4)) = ov;
            }
            __syncthreads();
        }
    }
}

// ---------------- Kernel 3: flash attention, 64-key staging, V in two 32-key halves ----------------
// Grid (4 sp, 4 b, 16 qtiles): XCD-local K/V slices. Block = 512 thr = 8 waves, wave owns 32 q.
__global__ __launch_bounds__(512, 1) void k_flash(const u16* __restrict__ Qw, const u16* __restrict__ Kw,
                                                  const u16* __restrict__ Vw, u16* __restrict__ Opart,
                                                  float* __restrict__ ml) {
    __shared__ u16 Ks[2][16384];    // [64 keys][256 ch], 16B-granule XOR(row&7) swizzle
    __shared__ u16 Vs[2][16384];    // two halves: [st][256 ch][32 keys], slot-swizzled
    const int sp = blockIdx.x, b = blockIdx.y;
    const int tid = threadIdx.x;
    const int w = tid >> 6, l = tid & 63;
    const int lr = l & 15, lg = l >> 4;
    const int qbase = blockIdx.z * 256 + w * 32;
    const int kb0 = sp * 1024;
    const size_t bN = (size_t)b * 4096;

    const u16* srcK = Kw + (bN + kb0 + (tid >> 5)) * 256 + (((tid & 31) * 8) ^ (((tid >> 5) & 7) * 8));
    const int u = tid & 255, sth = tid >> 8;   // V: 256-thread group per 32-key half
    const u16* srcV = Vw + ((size_t)b * 256 + (u >> 2)) * 4096 + kb0 + sth * 32 + (u & 3) * 8;
    const int vdst = sth * 8192 + u * 8;       // wave-uniform base + lane*8

#define STAGE(d, toff) { \
        const u16* sk_ = srcK + (size_t)(toff) * 16384; \
        const u16* sv_ = srcV + (toff) * 64; \
        gload16(sk_,               Ks[d] + tid * 8); \
        gload16(sk_ + 16 * 256,    Ks[d] + 4096 + tid * 8); \
        gload16(sk_ + 32 * 256,    Ks[d] + 8192 + tid * 8); \
        gload16(sk_ + 48 * 256,    Ks[d] + 12288 + tid * 8); \
        gload16(sv_,               Vs[d] + vdst); \
        gload16(sv_ + 64 * 4096,   Vs[d] + vdst + 2048); \
        gload16(sv_ + 128 * 4096,  Vs[d] + vdst + 4096); \
        gload16(sv_ + 192 * 4096,  Vs[d] + vdst + 6144); }

    const int c6 = (lr >> 2) & 1;
    int kofs[2];
#pragma unroll
    for (int n = 0; n < 2; ++n) kofs[n] = (n * 16 + lr) * 256 + ((lg * 8) ^ ((lr & 3) * 8));
    const int vslotA = ((lg ^ (lr >> 1)) * 4);   // r4-verified slot math (32-key rows)
    const int vslotB = vslotA ^ 16;

    short8 qf[2][8];
#pragma unroll
    for (int m = 0; m < 2; ++m)
#pragma unroll
        for (int cc = 0; cc < 8; ++cc)
            qf[m][cc] = *reinterpret_cast<const short8*>(&Qw[(bN + qbase + m * 16 + lr) * 256 + cc * 32 + lg * 8]);

    f32x4 Oa[2][16];
    float mr[2], lsum[2];
#pragma unroll
    for (int m = 0; m < 2; ++m) {
#pragma unroll
        for (int cs = 0; cs < 16; ++cs) Oa[m][cs] = f32x4{0.f, 0.f, 0.f, 0.f};
        mr[m] = -1e30f; lsum[m] = 0.f;
    }

    STAGE(0, 0);
    for (int kt = 0; kt < 16; ++kt) {
        const int d = kt & 1;
        asm volatile("s_waitcnt vmcnt(0)" ::: "memory");
        __builtin_amdgcn_sched_barrier(0);
        __builtin_amdgcn_s_barrier();
        if (kt < 15) STAGE(d ^ 1, kt + 1);

#pragma unroll
        for (int st = 0; st < 2; ++st) {
            const int kO = st * 8192;
            const int vH = st * 8192;           // V half base (u16)
            f32x4 sc[2][2];
#pragma unroll
            for (int m = 0; m < 2; ++m)
#pragma unroll
                for (int n = 0; n < 2; ++n) sc[m][n] = f32x4{0.f, 0.f, 0.f, 0.f};
            __builtin_amdgcn_s_setprio(1);
#pragma unroll
            for (int cc = 0; cc < 8; ++cc) {
                const int cb = ((cc ^ c6) << 5);
                short8 kf0 = *reinterpret_cast<const short8*>(&Ks[d][kO + kofs[0] + cb]);
                short8 kf1 = *reinterpret_cast<const short8*>(&Ks[d][kO + kofs[1] + cb]);
                sc[0][0] = __builtin_amdgcn_mfma_f32_16x16x32_bf16(kf0, qf[0][cc], sc[0][0], 0, 0, 0);
                sc[0][1] = __builtin_amdgcn_mfma_f32_16x16x32_bf16(kf1, qf[0][cc], sc[0][1], 0, 0, 0);
                sc[1][0] = __builtin_amdgcn_mfma_f32_16x16x32_bf16(kf0, qf[1][cc], sc[1][0], 0, 0, 0);
                sc[1][1] = __builtin_amdgcn_mfma_f32_16x16x32_bf16(kf1, qf[1][cc], sc[1][1], 0, 0, 0);
            }
            __builtin_amdgcn_s_setprio(0);

            float tmax[2];
            bool need = false;
#pragma unroll
            for (int m = 0; m < 2; ++m) {
                float tm = fmaxf(fmaxf(fmaxf(sc[m][0][0], sc[m][0][1]), fmaxf(sc[m][0][2], sc[m][0][3])),
                                 fmaxf(fmaxf(sc[m][1][0], sc[m][1][1]), fmaxf(sc[m][1][2], sc[m][1][3])));
                tm = fmaxf(tm, __shfl_xor(tm, 16));
                tm = fmaxf(tm, __shfl_xor(tm, 32));
                tmax[m] = tm;
                need = need || (tm > mr[m] + 8.f);
            }
            if (__any(need)) {   // defer-max (T13)
                float av[2][4];
#pragma unroll
                for (int m = 0; m < 2; ++m) {
                    float mn = fmaxf(mr[m], tmax[m]);
                    float al = exp2f(mr[m] - mn);
                    mr[m] = mn;
                    lsum[m] *= al;
#pragma unroll
                    for (int i = 0; i < 4; ++i) av[m][i] = __shfl(al, lg * 4 + i);
                }
#pragma unroll
                for (int m = 0; m < 2; ++m)
#pragma unroll
                    for (int cs = 0; cs < 16; ++cs)
#pragma unroll
                        for (int i = 0; i < 4; ++i) Oa[m][cs][i] *= av[m][i];
            }
            union { u32 uw[4]; short8 v; } pf[2];
#pragma unroll
            for (int m = 0; m < 2; ++m) {
                float p[8];
                float la = 0.f;
#pragma unroll
                for (int n = 0; n < 2; ++n)
#pragma unroll
                    for (int i = 0; i < 4; ++i) {
                        float pv = exp2f(sc[m][n][i] - mr[m]);
                        la += pv;
                        p[n * 4 + i] = pv;
                    }
                lsum[m] += la;
#pragma unroll
                for (int j = 0; j < 4; ++j) pf[m].uw[j] = cvtpk(p[2 * j], p[2 * j + 1]);
            }
            __builtin_amdgcn_s_setprio(1);
#pragma unroll
            for (int cs = 0; cs < 16; ++cs) {
                const int base = vH + (cs * 16 + lr) * 32;
                short4v lo = *reinterpret_cast<const short4v*>(&Vs[d][base + vslotA]);
                short4v hi = *reinterpret_cast<const short4v*>(&Vs[d][base + vslotB]);
                short8 vf = __builtin_shufflevector(lo, hi, 0, 1, 2, 3, 4, 5, 6, 7);
                Oa[0][cs] = __builtin_amdgcn_mfma_f32_16x16x32_bf16(pf[0].v, vf, Oa[0][cs], 0, 0, 0);
                Oa[1][cs] = __builtin_amdgcn_mfma_f32_16x16x32_bf16(pf[1].v, vf, Oa[1][cs], 0, 0, 0);
            }
            __builtin_amdgcn_s_setprio(0);
        }
    }
#undef STAGE

    float lt[2];
#pragma unroll
    for (int m = 0; m < 2; ++m) {
        float ts = lsum[m];
        ts += __shfl_xor(ts, 16);
        ts += __shfl_xor(ts, 32);
        lt[m] = ts;
    }
    const size_t obase = ((size_t)(b * 4 + sp) * 4096 + qbase);
#pragma unroll
    for (int m = 0; m < 2; ++m)
#pragma unroll
        for (int cs = 0; cs < 16; ++cs)
#pragma unroll
            for (int i = 0; i < 4; ++i)
                Opart[(obase + m * 16 + lg * 4 + i) * 256 + cs * 16 + lr] = f2bf(Oa[m][cs][i]);
    if (lg == 0) {
#pragma unroll
        for (int m = 0; m < 2; ++m) {
            size_t r = obase + m * 16 + lr;
            ml[r * 2]     = mr[m];
            ml[r * 2 + 1] = lt[m];
        }
    }
}

// ---------------- Kernel 3b: combine split-KV partials -> Obf (B,N,C) bf16 ----------------
__global__ __launch_bounds__(256) void k_comb(const u16* __restrict__ Opart, const float* __restrict__ ml,
                                              u16* __restrict__ Obf) {
    const int row = blockIdx.x * 8 + (threadIdx.x >> 5);   // b*4096 + n
    const int b = row >> 12;
    const int c0 = (threadIdx.x & 31) * 8;
    const size_t rbase = (size_t)b * 4 * 4096 + (row & 4095);
    float ms[4], lsv[4];
#pragma unroll
    for (int s = 0; s < 4; ++s) {
        ms[s]  = ml[(rbase + (size_t)s * 4096) * 2];
        lsv[s] = ml[(rbase + (size_t)s * 4096) * 2 + 1];
    }
    float M = fmaxf(fmaxf(ms[0], ms[1]), fmaxf(ms[2], ms[3]));
    float W[4], L = 0.f;
#pragma unroll
    for (int s = 0; s < 4; ++s) { W[s] = exp2f(ms[s] - M); L += W[s] * lsv[s]; }
    const float inv = 1.f / L;
    float o[8] = {};
#pragma unroll
    for (int s = 0; s < 4; ++s) {
        short8 v = *reinterpret_cast<const short8*>(&Opart[(rbase + (size_t)s * 4096) * 256 + c0]);
#pragma unroll
        for (int j = 0; j < 8; ++j) o[j] += W[s] * bf2f((u16)v[j]);
    }
    short8 r;
#pragma unroll
    for (int j = 0; j < 8; ++j) r[j] = (short)f2bf(o[j] * inv);
    *reinterpret_cast<short8*>(&Obf[(size_t)row * 256 + c0]) = r;
}

// ---------------- Kernel 4: proj as bf16 MFMA GEMM + bias + residual ----------------
__global__ __launch_bounds__(256) void k_proj(const u16* __restrict__ O, const u16* __restrict__ Wp,
                                              const float* __restrict__ proj_b, const float* __restrict__ x,
                                              float* __restrict__ out) {
    __shared__ float T[64][132];   // [c_local][n_local] f32
    const int b = blockIdx.z, c0 = blockIdx.x * 64, nb0 = blockIdx.y * 128;
    const int t = threadIdx.x, w = t >> 6, l = t & 63, lr = l & 15, lg = l >> 4;
    const size_t bN = (size_t)b * 4096;
    f32x4 acc[2][4];
#pragma unroll
    for (int m = 0; m < 2; ++m)
#pragma unroll
        for (int nf = 0; nf < 4; ++nf) acc[m][nf] = f32x4{0.f, 0.f, 0.f, 0.f};
    const u16* A0 = &O[(bN + nb0 + w * 32 + lr) * 256];
    const u16* A1 = A0 + 16 * 256;
#pragma unroll
    for (int cc = 0; cc < 8; ++cc) {
        short8 af0 = *reinterpret_cast<const short8*>(A0 + cc * 32 + lg * 8);
        short8 af1 = *reinterpret_cast<const short8*>(A1 + cc * 32 + lg * 8);
#pragma unroll
        for (int nf = 0; nf < 4; ++nf) {
            short8 bf = *reinterpret_cast<const short8*>(&Wp[(size_t)(c0 + nf * 16 + lr) * 256 + cc * 32 + lg * 8]);
            acc[0][nf] = __builtin_amdgcn_mfma_f32_16x16x32_bf16(af0, bf, acc[0][nf], 0, 0, 0);
            acc[1][nf] = __builtin_amdgcn_mfma_f32_16x16x32_bf16(af1, bf, acc[1][nf], 0, 0, 0);
        }
    }
#pragma unroll
    for (int m = 0; m < 2; ++m)
#pragma unroll
        for (int nf = 0; nf < 4; ++nf)
#pragma unroll
            for (int i = 0; i < 4; ++i)
                T[nf * 16 + lr][w * 32 + m * 16 + lg * 4 + i] = acc[m][nf][i];
    __syncthreads();
    const int cl = t >> 2, nbl = (t & 3) * 32;
    const float pb = proj_b[c0 + cl];
    const size_t base = ((size_t)b * 256 + c0 + cl) * 4096 + nb0 + nbl;
#pragma unroll
    for (int j = 0; j < 32; j += 4) {
        float4 xv = *reinterpret_cast<const float4*>(&x[base + j]);
        float4 r;
        r.x = xv.x + T[cl][nbl + j + 0] + pb;
        r.y = xv.y + T[cl][nbl + j + 1] + pb;
        r.z = xv.z + T[cl][nbl + j + 2] + pb;
        r.w = xv.w + T[cl][nbl + j + 3] + pb;
        *reinterpret_cast<float4*>(&out[base + j]) = r;
    }
}

extern "C" void kernel_launch(void* const* d_in, const int* in_sizes, int n_in,
                              void* d_out, int out_size, void* d_ws, size_t ws_size,
                              hipStream_t stream) {
    const float* x      = (const float*)d_in[0];
    const float* gngam  = (const float*)d_in[1];
    const float* gnbeta = (const float*)d_in[2];
    const float* qkv_w  = (const float*)d_in[3];
    const float* qkv_b  = (const float*)d_in[4];
    const float* proj_w = (const float*)d_in[5];
    const float* proj_b = (const float*)d_in[6];
    float* out = (float*)d_out;

    char* wsb = (char*)d_ws;
    float* stats = (float*)wsb;                       // 1 KB
    u16* Hbf   = (u16*)(wsb + 1024);                  // 8 MB (B,N,C)
    u16* Qws   = Hbf + 4194304;                       // 8 MB (B,N,C) pre-scaled
    u16* Kws   = Qws + 4194304;                       // 8 MB (B,N,C)
    u16* Vws   = Kws + 4194304;                       // 8 MB (B,C,N) slot-swizzled
    u16* W2q   = Vws + 4194304;                       // 384 KB
    u16* W2p   = W2q + 196608;                        // 128 KB
    u16* Opart = W2p + 65536;                         // 32 MB (B,S,N,C) unnormalized
    float* ml  = (float*)(Opart + 16777216);          // 512 KB (B,S,N,2)
    u16* Obf   = (u16*)(ml + 131072);                 // 8 MB (B,N,C)

    k_pre<<<288, 256, 0, stream>>>(x, stats, qkv_w, proj_w, W2q, W2p);
    k_norm<<<dim3(64, 4, 4), 256, 0, stream>>>(x, gngam, gnbeta, stats, Hbf);
    k_qkv<<<dim3(6, 32, 4), 256, 0, stream>>>(Hbf, W2q, qkv_b, Qws, Kws, Vws);
    k_flash<<<dim3(4, 4, 16), 512, 0, stream>>>(Qws, Kws, Vws, Opart, ml);
    k_comb<<<2048, 256, 0, stream>>>(Opart, ml, Obf);
    k_proj<<<dim3(4, 32, 4), 256, 0, stream>>>(Obf, W2p, proj_b, x, out);
}

// Round 12
// 196.927 us; speedup vs baseline: 1.0528x; 1.0269x over previous
//
#include <hip/hip_runtime.h>
#include <hip/hip_bf16.h>

typedef unsigned short u16;
typedef unsigned int u32;
typedef __attribute__((ext_vector_type(8))) short short8;
typedef __attribute__((ext_vector_type(4))) short short4v;
typedef __attribute__((ext_vector_type(4))) float f32x4;

static __device__ __forceinline__ u16 f2bf(float f) {
    union { float f; unsigned u; } a; a.f = f;
    unsigned u = a.u;
    u += 0x7FFFu + ((u >> 16) & 1u);   // RNE; inputs are finite
    return (u16)(u >> 16);
}
static __device__ __forceinline__ float bf2f(u16 h) {
    union { u32 u; float f; } a; a.u = ((u32)h) << 16; return a.f;
}
static __device__ __forceinline__ u32 cvtpk(float lo, float hi) {   // [bf16(hi)<<16 | bf16(lo)]
    u32 r; asm("v_cvt_pk_bf16_f32 %0, %1, %2" : "=v"(r) : "v"(lo), "v"(hi)); return r;
}
static __device__ __forceinline__ void gload16(const u16* g, u16* l) {
    __builtin_amdgcn_global_load_lds((const __attribute__((address_space(1))) u32*)(const void*)g,
                                     (__attribute__((address_space(3))) u32*)(void*)l, 16, 0, 0);
}

// ---------------- Kernel 1: GroupNorm stats (blocks 0-31) + weight fp32->bf16 (blocks 32-287) ----
__global__ __launch_bounds__(256) void k_pre(const float* __restrict__ x, float* __restrict__ stats,
                                             const float* __restrict__ qw, const float* __restrict__ pw,
                                             u16* __restrict__ q2, u16* __restrict__ p2) {
    const int t = threadIdx.x;
    if (blockIdx.x >= 32) {
        const int i = ((int)blockIdx.x - 32) * 1024 + t * 4;
        const float* src; u16* dst;
        if (i < 196608) { src = qw + i; dst = q2 + i; }
        else            { src = pw + (i - 196608); dst = p2 + (i - 196608); }
        float4 v = *reinterpret_cast<const float4*>(src);
        u16 o[4] = { f2bf(v.x), f2bf(v.y), f2bf(v.z), f2bf(v.w) };
        *reinterpret_cast<uint2*>(dst) = *reinterpret_cast<uint2*>(o);
        return;
    }
    const int bg = blockIdx.x;
    const float* p = x + (size_t)bg * (32 * 4096);
    float s = 0.f, ss = 0.f;
    for (int i = t * 4; i < 32 * 4096; i += 256 * 4) {
        float4 v = *reinterpret_cast<const float4*>(p + i);
        s  += v.x + v.y + v.z + v.w;
        ss += v.x * v.x + v.y * v.y + v.z * v.z + v.w * v.w;
    }
    for (int off = 1; off < 64; off <<= 1) { s += __shfl_xor(s, off); ss += __shfl_xor(ss, off); }
    __shared__ float ls[4], lss[4];
    if ((t & 63) == 0) { ls[t >> 6] = s; lss[t >> 6] = ss; }
    __syncthreads();
    if (t == 0) {
        float S  = ls[0] + ls[1] + ls[2] + ls[3];
        float SS = lss[0] + lss[1] + lss[2] + lss[3];
        const float inv = 1.f / (32.f * 4096.f);
        float mu  = S * inv;
        float var = SS * inv - mu * mu;
        stats[bg * 2]     = mu;
        stats[bg * 2 + 1] = rsqrtf(var + 1e-5f);
    }
}

// ---------------- Kernel 1c: GN-normalize + transpose -> Hbf (B,N,C) bf16 ----------------
__global__ __launch_bounds__(256) void k_norm(const float* __restrict__ x, const float* __restrict__ gamma,
                                              const float* __restrict__ beta, const float* __restrict__ stats,
                                              u16* __restrict__ H) {
    __shared__ u16 T[64][72];   // [c_local][n_local]
    const int b = blockIdx.z, c0 = blockIdx.y * 64, n0 = blockIdx.x * 64;
    const int t = threadIdx.x;
    const int cl = t >> 2, nb = (t & 3) * 16;
    const int c = c0 + cl;
    const float mu = stats[(b * 8 + (c >> 5)) * 2];
    const float rstd = stats[(b * 8 + (c >> 5)) * 2 + 1];
    const float ga = gamma[c] * rstd, be = beta[c] - mu * ga;
    const float* xp = &x[((size_t)b * 256 + c) * 4096 + n0 + nb];
#pragma unroll
    for (int j = 0; j < 16; j += 4) {
        float4 v = *reinterpret_cast<const float4*>(xp + j);
        T[cl][nb + j + 0] = f2bf(v.x * ga + be);
        T[cl][nb + j + 1] = f2bf(v.y * ga + be);
        T[cl][nb + j + 2] = f2bf(v.z * ga + be);
        T[cl][nb + j + 3] = f2bf(v.w * ga + be);
    }
    __syncthreads();
    const int nl = t >> 2, cb = (t & 3) * 16;
    short8 s0, s1;
#pragma unroll
    for (int j = 0; j < 8; ++j) { s0[j] = (short)T[cb + j][nl]; s1[j] = (short)T[cb + 8 + j][nl]; }
    u16* dst = &H[((size_t)b * 4096 + n0 + nl) * 256 + c0 + cb];
    *reinterpret_cast<short8*>(dst)     = s0;
    *reinterpret_cast<short8*>(dst + 8) = s1;
}

// ---------------- Kernel 2: QKV as bf16 MFMA GEMM ----------------
// Writes: Q (B,N,C) scaled by 1/16*log2(e) ; K (B,N,C) ; V (B,C,N) with per-32-key-block
// XOR-swizzle: key-group g (4 keys) stored at slot g ^ ((ch>>1)&7).
__global__ __launch_bounds__(256) void k_qkv(const u16* __restrict__ H, const u16* __restrict__ W2,
                                             const float* __restrict__ qkv_b,
                                             u16* __restrict__ Q, u16* __restrict__ K, u16* __restrict__ V) {
    __shared__ u16 T[9216];   // Q/K: [128][72] ; V: [64][144]
    const int b = blockIdx.z, o0 = blockIdx.x * 64, nb0 = blockIdx.y * 128;
    const int t = threadIdx.x, w = t >> 6, l = t & 63, lr = l & 15, lg = l >> 4;
    const size_t bN = (size_t)b * 4096;
    f32x4 acc[2][4];
#pragma unroll
    for (int m = 0; m < 2; ++m)
#pragma unroll
        for (int nf = 0; nf < 4; ++nf) acc[m][nf] = f32x4{0.f, 0.f, 0.f, 0.f};
    const u16* A0 = &H[(bN + nb0 + w * 32 + lr) * 256];
    const u16* A1 = A0 + 16 * 256;
#pragma unroll
    for (int cc = 0; cc < 8; ++cc) {
        short8 af0 = *reinterpret_cast<const short8*>(A0 + cc * 32 + lg * 8);
        short8 af1 = *reinterpret_cast<const short8*>(A1 + cc * 32 + lg * 8);
#pragma unroll
        for (int nf = 0; nf < 4; ++nf) {
            short8 bf = *reinterpret_cast<const short8*>(&W2[(size_t)(o0 + nf * 16 + lr) * 256 + cc * 32 + lg * 8]);
            acc[0][nf] = __builtin_amdgcn_mfma_f32_16x16x32_bf16(af0, bf, acc[0][nf], 0, 0, 0);
            acc[1][nf] = __builtin_amdgcn_mfma_f32_16x16x32_bf16(af1, bf, acc[1][nf], 0, 0, 0);
        }
    }
    const int og = o0 >> 8;   // 0=Q, 1=K, 2=V
    const float scal = (og == 0) ? 0.0625f * 1.44269504f : 1.0f;   // fold C^-0.5 * log2(e) into Q
    float bias[4];
#pragma unroll
    for (int nf = 0; nf < 4; ++nf) bias[nf] = qkv_b[o0 + nf * 16 + lr];
    if (og < 2) {
#pragma unroll
        for (int m = 0; m < 2; ++m)
#pragma unroll
            for (int nf = 0; nf < 4; ++nf)
#pragma unroll
                for (int i = 0; i < 4; ++i)
                    T[(w * 32 + m * 16 + lg * 4 + i) * 72 + nf * 16 + lr] = f2bf((acc[m][nf][i] + bias[nf]) * scal);
        __syncthreads();
        const int rl = t >> 1, half = (t & 1) * 32;
        u16* dst = (og == 0 ? Q : K) + (bN + nb0 + rl) * 256 + (o0 & 255) + half;
#pragma unroll
        for (int j = 0; j < 4; ++j)
            *reinterpret_cast<short8*>(dst + j * 8) = *reinterpret_cast<short8*>(&T[rl * 72 + half + j * 8]);
    } else {
#pragma unroll
        for (int m = 0; m < 2; ++m)
#pragma unroll
            for (int nf = 0; nf < 4; ++nf)
#pragma unroll
                for (int i = 0; i < 4; ++i)
                    T[(nf * 16 + lr) * 144 + w * 32 + m * 16 + lg * 4 + i] = f2bf(acc[m][nf][i] + bias[nf]);
        __syncthreads();
        const int ol = t >> 2, nbl = (t & 3) * 32;
        const int s_ = (ol >> 1) & 7;                    // == (global_ch>>1)&7 since o0%64==0
        u16* dst = V + ((size_t)b * 256 + (o0 - 512) + ol) * 4096 + nb0 + nbl;
#pragma unroll
        for (int j = 0; j < 4; ++j) {
            short8 vv = *reinterpret_cast<short8*>(&T[ol * 144 + nbl + j * 8]);
            short8 ov;
            if (s_ & 1) ov = short8{vv[4], vv[5], vv[6], vv[7], vv[0], vv[1], vv[2], vv[3]};
            else        ov = vv;
            *reinterpret_cast<short8*>(dst + (((2 * j) ^ (s_ & 6)) * 4)) = ov;
        }
    }
}

// ---------------- Kernel 3: flash attention, 64-key staging, V in two 32-key halves ----------------
// Grid (4 sp, 4 b, 16 qtiles): XCD-local K/V slices. Block = 512 thr = 8 waves, wave owns 32 q.
__global__ __launch_bounds__(512, 1) void k_flash(const u16* __restrict__ Qw, const u16* __restrict__ Kw,
                                                  const u16* __restrict__ Vw, u16* __restrict__ Opart,
                                                  float* __restrict__ ml) {
    __shared__ u16 Ks[2][16384];    // [64 keys][256 ch], 16B-granule XOR(row&7) swizzle
    __shared__ u16 Vs[2][16384];    // two halves: [st][256 ch][32 keys], slot-swizzled
    const int sp = blockIdx.x, b = blockIdx.y;
    const int tid = threadIdx.x;
    const int w = tid >> 6, l = tid & 63;
    const int lr = l & 15, lg = l >> 4;
    const int qbase = blockIdx.z * 256 + w * 32;
    const int kb0 = sp * 1024;
    const size_t bN = (size_t)b * 4096;

    const u16* srcK = Kw + (bN + kb0 + (tid >> 5)) * 256 + (((tid & 31) * 8) ^ (((tid >> 5) & 7) * 8));
    const int u = tid & 255, sth = tid >> 8;   // V: 256-thread group per 32-key half
    const u16* srcV = Vw + ((size_t)b * 256 + (u >> 2)) * 4096 + kb0 + sth * 32 + (u & 3) * 8;
    const int vdst = sth * 8192 + u * 8;       // wave-uniform base + lane*8

#define STAGE(d, toff) { \
        const u16* sk_ = srcK + (size_t)(toff) * 16384; \
        const u16* sv_ = srcV + (toff) * 64; \
        gload16(sk_,               Ks[d] + tid * 8); \
        gload16(sk_ + 16 * 256,    Ks[d] + 4096 + tid * 8); \
        gload16(sk_ + 32 * 256,    Ks[d] + 8192 + tid * 8); \
        gload16(sk_ + 48 * 256,    Ks[d] + 12288 + tid * 8); \
        gload16(sv_,               Vs[d] + vdst); \
        gload16(sv_ + 64 * 4096,   Vs[d] + vdst + 2048); \
        gload16(sv_ + 128 * 4096,  Vs[d] + vdst + 4096); \
        gload16(sv_ + 192 * 4096,  Vs[d] + vdst + 6144); }

    const int c6 = (lr >> 2) & 1;
    int kofs[2];
#pragma unroll
    for (int n = 0; n < 2; ++n) kofs[n] = (n * 16 + lr) * 256 + ((lg * 8) ^ ((lr & 3) * 8));
    const int vslotA = ((lg ^ (lr >> 1)) * 4);   // r4-verified slot math (32-key rows)
    const int vslotB = vslotA ^ 16;

    short8 qf[2][8];
#pragma unroll
    for (int m = 0; m < 2; ++m)
#pragma unroll
        for (int cc = 0; cc < 8; ++cc)
            qf[m][cc] = *reinterpret_cast<const short8*>(&Qw[(bN + qbase + m * 16 + lr) * 256 + cc * 32 + lg * 8]);

    f32x4 Oa[2][16];
    float mr[2], lsum[2];
#pragma unroll
    for (int m = 0; m < 2; ++m) {
#pragma unroll
        for (int cs = 0; cs < 16; ++cs) Oa[m][cs] = f32x4{0.f, 0.f, 0.f, 0.f};
        mr[m] = -1e30f; lsum[m] = 0.f;
    }

    STAGE(0, 0);
    for (int kt = 0; kt < 16; ++kt) {
        const int d = kt & 1;
        asm volatile("s_waitcnt vmcnt(0)" ::: "memory");
        __builtin_amdgcn_sched_barrier(0);
        __builtin_amdgcn_s_barrier();
        if (kt < 15) STAGE(d ^ 1, kt + 1);

#pragma unroll
        for (int st = 0; st < 2; ++st) {
            const int kO = st * 8192;
            const int vH = st * 8192;           // V half base (u16)
            f32x4 sc[2][2];
#pragma unroll
            for (int m = 0; m < 2; ++m)
#pragma unroll
                for (int n = 0; n < 2; ++n) sc[m][n] = f32x4{0.f, 0.f, 0.f, 0.f};
            __builtin_amdgcn_s_setprio(1);
#pragma unroll
            for (int cc = 0; cc < 8; ++cc) {
                const int cb = ((cc ^ c6) << 5);
                short8 kf0 = *reinterpret_cast<const short8*>(&Ks[d][kO + kofs[0] + cb]);
                short8 kf1 = *reinterpret_cast<const short8*>(&Ks[d][kO + kofs[1] + cb]);
                sc[0][0] = __builtin_amdgcn_mfma_f32_16x16x32_bf16(kf0, qf[0][cc], sc[0][0], 0, 0, 0);
                sc[0][1] = __builtin_amdgcn_mfma_f32_16x16x32_bf16(kf1, qf[0][cc], sc[0][1], 0, 0, 0);
                sc[1][0] = __builtin_amdgcn_mfma_f32_16x16x32_bf16(kf0, qf[1][cc], sc[1][0], 0, 0, 0);
                sc[1][1] = __builtin_amdgcn_mfma_f32_16x16x32_bf16(kf1, qf[1][cc], sc[1][1], 0, 0, 0);
            }
            __builtin_amdgcn_s_setprio(0);

            float tmax[2];
            bool need = false;
#pragma unroll
            for (int m = 0; m < 2; ++m) {
                float tm = fmaxf(fmaxf(fmaxf(sc[m][0][0], sc[m][0][1]), fmaxf(sc[m][0][2], sc[m][0][3])),
                                 fmaxf(fmaxf(sc[m][1][0], sc[m][1][1]), fmaxf(sc[m][1][2], sc[m][1][3])));
                tm = fmaxf(tm, __shfl_xor(tm, 16));
                tm = fmaxf(tm, __shfl_xor(tm, 32));
                tmax[m] = tm;
                need = need || (tm > mr[m] + 8.f);
            }
            if (__any(need)) {   // defer-max (T13)
                float av[2][4];
#pragma unroll
                for (int m = 0; m < 2; ++m) {
                    float mn = fmaxf(mr[m], tmax[m]);
                    float al = exp2f(mr[m] - mn);
                    mr[m] = mn;
                    lsum[m] *= al;
#pragma unroll
                    for (int i = 0; i < 4; ++i) av[m][i] = __shfl(al, lg * 4 + i);
                }
#pragma unroll
                for (int m = 0; m < 2; ++m)
#pragma unroll
                    for (int cs = 0; cs < 16; ++cs)
#pragma unroll
                        for (int i = 0; i < 4; ++i) Oa[m][cs][i] *= av[m][i];
            }
            union { u32 uw[4]; short8 v; } pf[2];
#pragma unroll
            for (int m = 0; m < 2; ++m) {
                float p[8];
                float la = 0.f;
#pragma unroll
                for (int n = 0; n < 2; ++n)
#pragma unroll
                    for (int i = 0; i < 4; ++i) {
                        float pv = exp2f(sc[m][n][i] - mr[m]);
                        la += pv;
                        p[n * 4 + i] = pv;
                    }
                lsum[m] += la;
#pragma unroll
                for (int j = 0; j < 4; ++j) pf[m].uw[j] = cvtpk(p[2 * j], p[2 * j + 1]);
            }
            __builtin_amdgcn_s_setprio(1);
#pragma unroll
            for (int cs = 0; cs < 16; ++cs) {
                const int base = vH + (cs * 16 + lr) * 32;
                short4v lo = *reinterpret_cast<const short4v*>(&Vs[d][base + vslotA]);
                short4v hi = *reinterpret_cast<const short4v*>(&Vs[d][base + vslotB]);
                short8 vf = __builtin_shufflevector(lo, hi, 0, 1, 2, 3, 4, 5, 6, 7);
                Oa[0][cs] = __builtin_amdgcn_mfma_f32_16x16x32_bf16(pf[0].v, vf, Oa[0][cs], 0, 0, 0);
                Oa[1][cs] = __builtin_amdgcn_mfma_f32_16x16x32_bf16(pf[1].v, vf, Oa[1][cs], 0, 0, 0);
            }
            __builtin_amdgcn_s_setprio(0);
        }
    }
#undef STAGE

    float lt[2];
#pragma unroll
    for (int m = 0; m < 2; ++m) {
        float ts = lsum[m];
        ts += __shfl_xor(ts, 16);
        ts += __shfl_xor(ts, 32);
        lt[m] = ts;
    }
    const size_t obase = ((size_t)(b * 4 + sp) * 4096 + qbase);
#pragma unroll
    for (int m = 0; m < 2; ++m)
#pragma unroll
        for (int cs = 0; cs < 16; ++cs)
#pragma unroll
            for (int i = 0; i < 4; ++i)
                Opart[(obase + m * 16 + lg * 4 + i) * 256 + cs * 16 + lr] = f2bf(Oa[m][cs][i]);
    if (lg == 0) {
#pragma unroll
        for (int m = 0; m < 2; ++m) {
            size_t r = obase + m * 16 + lr;
            ml[r * 2]     = mr[m];
            ml[r * 2 + 1] = lt[m];
        }
    }
}

// ---------------- Kernel 3b: combine split-KV partials -> Obf (B,N,C) bf16 ----------------
__global__ __launch_bounds__(256) void k_comb(const u16* __restrict__ Opart, const float* __restrict__ ml,
                                              u16* __restrict__ Obf) {
    const int row = blockIdx.x * 8 + (threadIdx.x >> 5);   // b*4096 + n
    const int b = row >> 12;
    const int c0 = (threadIdx.x & 31) * 8;
    const size_t rbase = (size_t)b * 4 * 4096 + (row & 4095);
    float ms[4], lsv[4];
#pragma unroll
    for (int s = 0; s < 4; ++s) {
        ms[s]  = ml[(rbase + (size_t)s * 4096) * 2];
        lsv[s] = ml[(rbase + (size_t)s * 4096) * 2 + 1];
    }
    float M = fmaxf(fmaxf(ms[0], ms[1]), fmaxf(ms[2], ms[3]));
    float W[4], L = 0.f;
#pragma unroll
    for (int s = 0; s < 4; ++s) { W[s] = exp2f(ms[s] - M); L += W[s] * lsv[s]; }
    const float inv = 1.f / L;
    float o[8] = {};
#pragma unroll
    for (int s = 0; s < 4; ++s) {
        short8 v = *reinterpret_cast<const short8*>(&Opart[(rbase + (size_t)s * 4096) * 256 + c0]);
#pragma unroll
        for (int j = 0; j < 8; ++j) o[j] += W[s] * bf2f((u16)v[j]);
    }
    short8 r;
#pragma unroll
    for (int j = 0; j < 8; ++j) r[j] = (short)f2bf(o[j] * inv);
    *reinterpret_cast<short8*>(&Obf[(size_t)row * 256 + c0]) = r;
}

// ---------------- Kernel 4: proj as bf16 MFMA GEMM + bias + residual ----------------
__global__ __launch_bounds__(256) void k_proj(const u16* __restrict__ O, const u16* __restrict__ Wp,
                                              const float* __restrict__ proj_b, const float* __restrict__ x,
                                              float* __restrict__ out) {
    __shared__ float T[64][132];   // [c_local][n_local] f32
    const int b = blockIdx.z, c0 = blockIdx.x * 64, nb0 = blockIdx.y * 128;
    const int t = threadIdx.x, w = t >> 6, l = t & 63, lr = l & 15, lg = l >> 4;
    const size_t bN = (size_t)b * 4096;
    f32x4 acc[2][4];
#pragma unroll
    for (int m = 0; m < 2; ++m)
#pragma unroll
        for (int nf = 0; nf < 4; ++nf) acc[m][nf] = f32x4{0.f, 0.f, 0.f, 0.f};
    const u16* A0 = &O[(bN + nb0 + w * 32 + lr) * 256];
    const u16* A1 = A0 + 16 * 256;
#pragma unroll
    for (int cc = 0; cc < 8; ++cc) {
        short8 af0 = *reinterpret_cast<const short8*>(A0 + cc * 32 + lg * 8);
        short8 af1 = *reinterpret_cast<const short8*>(A1 + cc * 32 + lg * 8);
#pragma unroll
        for (int nf = 0; nf < 4; ++nf) {
            short8 bf = *reinterpret_cast<const short8*>(&Wp[(size_t)(c0 + nf * 16 + lr) * 256 + cc * 32 + lg * 8]);
            acc[0][nf] = __builtin_amdgcn_mfma_f32_16x16x32_bf16(af0, bf, acc[0][nf], 0, 0, 0);
            acc[1][nf] = __builtin_amdgcn_mfma_f32_16x16x32_bf16(af1, bf, acc[1][nf], 0, 0, 0);
        }
    }
#pragma unroll
    for (int m = 0; m < 2; ++m)
#pragma unroll
        for (int nf = 0; nf < 4; ++nf)
#pragma unroll
            for (int i = 0; i < 4; ++i)
                T[nf * 16 + lr][w * 32 + m * 16 + lg * 4 + i] = acc[m][nf][i];
    __syncthreads();
    const int cl = t >> 2, nbl = (t & 3) * 32;
    const float pb = proj_b[c0 + cl];
    const size_t base = ((size_t)b * 256 + c0 + cl) * 4096 + nb0 + nbl;
#pragma unroll
    for (int j = 0; j < 32; j += 4) {
        float4 xv = *reinterpret_cast<const float4*>(&x[base + j]);
        float4 r;
        r.x = xv.x + T[cl][nbl + j + 0] + pb;
        r.y = xv.y + T[cl][nbl + j + 1] + pb;
        r.z = xv.z + T[cl][nbl + j + 2] + pb;
        r.w = xv.w + T[cl][nbl + j + 3] + pb;
        *reinterpret_cast<float4*>(&out[base + j]) = r;
    }
}

extern "C" void kernel_launch(void* const* d_in, const int* in_sizes, int n_in,
                              void* d_out, int out_size, void* d_ws, size_t ws_size,
                              hipStream_t stream) {
    const float* x      = (const float*)d_in[0];
    const float* gngam  = (const float*)d_in[1];
    const float* gnbeta = (const float*)d_in[2];
    const float* qkv_w  = (const float*)d_in[3];
    const float* qkv_b  = (const float*)d_in[4];
    const float* proj_w = (const float*)d_in[5];
    const float* proj_b = (const float*)d_in[6];
    float* out = (float*)d_out;

    char* wsb = (char*)d_ws;
    float* stats = (float*)wsb;                       // 1 KB
    u16* Hbf   = (u16*)(wsb + 1024);                  // 8 MB (B,N,C)
    u16* Qws   = Hbf + 4194304;                       // 8 MB (B,N,C) pre-scaled
    u16* Kws   = Qws + 4194304;                       // 8 MB (B,N,C)
    u16* Vws   = Kws + 4194304;                       // 8 MB (B,C,N) slot-swizzled
    u16* W2q   = Vws + 4194304;                       // 384 KB
    u16* W2p   = W2q + 196608;                        // 128 KB
    u16* Opart = W2p + 65536;                         // 32 MB (B,S,N,C) unnormalized
    float* ml  = (float*)(Opart + 16777216);          // 512 KB (B,S,N,2)
    u16* Obf   = (u16*)(ml + 131072);                 // 8 MB (B,N,C)

    k_pre<<<288, 256, 0, stream>>>(x, stats, qkv_w, proj_w, W2q, W2p);
    k_norm<<<dim3(64, 4, 4), 256, 0, stream>>>(x, gngam, gnbeta, stats, Hbf);
    k_qkv<<<dim3(12, 32, 4), 256, 0, stream>>>(Hbf, W2q, qkv_b, Qws, Kws, Vws);
    k_flash<<<dim3(4, 4, 16), 512, 0, stream>>>(Qws, Kws, Vws, Opart, ml);
    k_comb<<<2048, 256, 0, stream>>>(Opart, ml, Obf);
    k_proj<<<dim3(4, 32, 4), 256, 0, stream>>>(Obf, W2p, proj_b, x, out);
}

// Round 13
// 164.569 us; speedup vs baseline: 1.2598x; 1.1966x over previous
//
#include <hip/hip_runtime.h>
#include <hip/hip_bf16.h>

typedef unsigned short u16;
typedef unsigned int u32;
typedef __attribute__((ext_vector_type(8))) short short8;
typedef __attribute__((ext_vector_type(4))) short short4v;
typedef __attribute__((ext_vector_type(4))) float f32x4;

static __device__ __forceinline__ u16 f2bf(float f) {
    union { float f; unsigned u; } a; a.f = f;
    unsigned u = a.u;
    u += 0x7FFFu + ((u >> 16) & 1u);   // RNE; inputs are finite
    return (u16)(u >> 16);
}
static __device__ __forceinline__ float bf2f(u16 h) {
    union { u32 u; float f; } a; a.u = ((u32)h) << 16; return a.f;
}
static __device__ __forceinline__ u32 cvtpk(float lo, float hi) {   // [bf16(hi)<<16 | bf16(lo)]
    u32 r; asm("v_cvt_pk_bf16_f32 %0, %1, %2" : "=v"(r) : "v"(lo), "v"(hi)); return r;
}
static __device__ __forceinline__ void gload16(const u16* g, u16* l) {
    __builtin_amdgcn_global_load_lds((const __attribute__((address_space(1))) u32*)(const void*)g,
                                     (__attribute__((address_space(3))) u32*)(void*)l, 16, 0, 0);
}

// ---------------- Kernel 1: GN partial stats (blocks 0-255) + weight fp32->bf16 (blocks 256-511) ----
// Stats: 8 slice-blocks per (b,g); each reduces 16384 floats -> partial (sum, sumsq).
__global__ __launch_bounds__(256) void k_pre(const float* __restrict__ x, float* __restrict__ pstats,
                                             const float* __restrict__ qw, const float* __restrict__ pw,
                                             u16* __restrict__ q2, u16* __restrict__ p2) {
    const int t = threadIdx.x;
    if (blockIdx.x >= 256) {
        const int i = ((int)blockIdx.x - 256) * 1024 + t * 4;
        const float* src; u16* dst;
        if (i < 196608) { src = qw + i; dst = q2 + i; }
        else            { src = pw + (i - 196608); dst = p2 + (i - 196608); }
        float4 v = *reinterpret_cast<const float4*>(src);
        u16 o[4] = { f2bf(v.x), f2bf(v.y), f2bf(v.z), f2bf(v.w) };
        *reinterpret_cast<uint2*>(dst) = *reinterpret_cast<uint2*>(o);
        return;
    }
    const int bg = blockIdx.x >> 3, sl = blockIdx.x & 7;
    const float* p = x + (size_t)bg * 131072 + sl * 16384;
    float s = 0.f, ss = 0.f;
#pragma unroll
    for (int i = t * 4; i < 16384; i += 256 * 4) {
        float4 v = *reinterpret_cast<const float4*>(p + i);
        s  += v.x + v.y + v.z + v.w;
        ss += v.x * v.x + v.y * v.y + v.z * v.z + v.w * v.w;
    }
    for (int off = 1; off < 64; off <<= 1) { s += __shfl_xor(s, off); ss += __shfl_xor(ss, off); }
    __shared__ float ls[4], lss[4];
    if ((t & 63) == 0) { ls[t >> 6] = s; lss[t >> 6] = ss; }
    __syncthreads();
    if (t == 0) {
        pstats[(bg * 8 + sl) * 2]     = ls[0] + ls[1] + ls[2] + ls[3];
        pstats[(bg * 8 + sl) * 2 + 1] = lss[0] + lss[1] + lss[2] + lss[3];
    }
}

// ---------------- Kernel 1c: finalize stats + GN-normalize + transpose -> Hbf (B,N,C) bf16 ----------
__global__ __launch_bounds__(256) void k_norm(const float* __restrict__ x, const float* __restrict__ gamma,
                                              const float* __restrict__ beta, const float* __restrict__ pstats,
                                              u16* __restrict__ H) {
    __shared__ u16 T[64][72];   // [c_local][n_local]
    __shared__ float smu[2], srs[2];
    const int b = blockIdx.z, c0 = blockIdx.y * 64, n0 = blockIdx.x * 64;
    const int t = threadIdx.x;
    if (t < 2) {   // finalize the block's 2 groups from 8 partials each
        const int g = (c0 >> 5) + t;
        float S = 0.f, SS = 0.f;
#pragma unroll
        for (int sl = 0; sl < 8; ++sl) {
            S  += pstats[((b * 8 + g) * 8 + sl) * 2];
            SS += pstats[((b * 8 + g) * 8 + sl) * 2 + 1];
        }
        const float inv = 1.f / (32.f * 4096.f);
        float mu  = S * inv;
        float var = SS * inv - mu * mu;
        smu[t] = mu;
        srs[t] = rsqrtf(var + 1e-5f);
    }
    __syncthreads();
    const int cl = t >> 2, nb = (t & 3) * 16;
    const int c = c0 + cl;
    const float mu = smu[cl >> 5];
    const float rstd = srs[cl >> 5];
    const float ga = gamma[c] * rstd, be = beta[c] - mu * ga;
    const float* xp = &x[((size_t)b * 256 + c) * 4096 + n0 + nb];
#pragma unroll
    for (int j = 0; j < 16; j += 4) {
        float4 v = *reinterpret_cast<const float4*>(xp + j);
        T[cl][nb + j + 0] = f2bf(v.x * ga + be);
        T[cl][nb + j + 1] = f2bf(v.y * ga + be);
        T[cl][nb + j + 2] = f2bf(v.z * ga + be);
        T[cl][nb + j + 3] = f2bf(v.w * ga + be);
    }
    __syncthreads();
    const int nl = t >> 2, cb = (t & 3) * 16;
    short8 s0, s1;
#pragma unroll
    for (int j = 0; j < 8; ++j) { s0[j] = (short)T[cb + j][nl]; s1[j] = (short)T[cb + 8 + j][nl]; }
    u16* dst = &H[((size_t)b * 4096 + n0 + nl) * 256 + c0 + cb];
    *reinterpret_cast<short8*>(dst)     = s0;
    *reinterpret_cast<short8*>(dst + 8) = s1;
}

// ---------------- Kernel 2: QKV as bf16 MFMA GEMM ----------------
// Writes: Q (B,N,C) scaled by 1/16*log2(e) ; K (B,N,C) ; V (B,C,N) with per-32-key-block
// XOR-swizzle: key-group g (4 keys) stored at slot g ^ ((ch>>1)&7).
__global__ __launch_bounds__(256) void k_qkv(const u16* __restrict__ H, const u16* __restrict__ W2,
                                             const float* __restrict__ qkv_b,
                                             u16* __restrict__ Q, u16* __restrict__ K, u16* __restrict__ V) {
    __shared__ u16 T[9216];   // Q/K: [128][72] ; V: [64][144]
    const int b = blockIdx.z, o0 = blockIdx.x * 64, nb0 = blockIdx.y * 128;
    const int t = threadIdx.x, w = t >> 6, l = t & 63, lr = l & 15, lg = l >> 4;
    const size_t bN = (size_t)b * 4096;
    f32x4 acc[2][4];
#pragma unroll
    for (int m = 0; m < 2; ++m)
#pragma unroll
        for (int nf = 0; nf < 4; ++nf) acc[m][nf] = f32x4{0.f, 0.f, 0.f, 0.f};
    const u16* A0 = &H[(bN + nb0 + w * 32 + lr) * 256];
    const u16* A1 = A0 + 16 * 256;
#pragma unroll
    for (int cc = 0; cc < 8; ++cc) {
        short8 af0 = *reinterpret_cast<const short8*>(A0 + cc * 32 + lg * 8);
        short8 af1 = *reinterpret_cast<const short8*>(A1 + cc * 32 + lg * 8);
#pragma unroll
        for (int nf = 0; nf < 4; ++nf) {
            short8 bf = *reinterpret_cast<const short8*>(&W2[(size_t)(o0 + nf * 16 + lr) * 256 + cc * 32 + lg * 8]);
            acc[0][nf] = __builtin_amdgcn_mfma_f32_16x16x32_bf16(af0, bf, acc[0][nf], 0, 0, 0);
            acc[1][nf] = __builtin_amdgcn_mfma_f32_16x16x32_bf16(af1, bf, acc[1][nf], 0, 0, 0);
        }
    }
    const int og = o0 >> 8;   // 0=Q, 1=K, 2=V
    const float scal = (og == 0) ? 0.0625f * 1.44269504f : 1.0f;   // fold C^-0.5 * log2(e) into Q
    float bias[4];
#pragma unroll
    for (int nf = 0; nf < 4; ++nf) bias[nf] = qkv_b[o0 + nf * 16 + lr];
    if (og < 2) {
#pragma unroll
        for (int m = 0; m < 2; ++m)
#pragma unroll
            for (int nf = 0; nf < 4; ++nf)
#pragma unroll
                for (int i = 0; i < 4; ++i)
                    T[(w * 32 + m * 16 + lg * 4 + i) * 72 + nf * 16 + lr] = f2bf((acc[m][nf][i] + bias[nf]) * scal);
        __syncthreads();
        const int rl = t >> 1, half = (t & 1) * 32;
        u16* dst = (og == 0 ? Q : K) + (bN + nb0 + rl) * 256 + (o0 & 255) + half;
#pragma unroll
        for (int j = 0; j < 4; ++j)
            *reinterpret_cast<short8*>(dst + j * 8) = *reinterpret_cast<short8*>(&T[rl * 72 + half + j * 8]);
    } else {
#pragma unroll
        for (int m = 0; m < 2; ++m)
#pragma unroll
            for (int nf = 0; nf < 4; ++nf)
#pragma unroll
                for (int i = 0; i < 4; ++i)
                    T[(nf * 16 + lr) * 144 + w * 32 + m * 16 + lg * 4 + i] = f2bf(acc[m][nf][i] + bias[nf]);
        __syncthreads();
        const int ol = t >> 2, nbl = (t & 3) * 32;
        const int s_ = (ol >> 1) & 7;                    // == (global_ch>>1)&7 since o0%64==0
        u16* dst = V + ((size_t)b * 256 + (o0 - 512) + ol) * 4096 + nb0 + nbl;
#pragma unroll
        for (int j = 0; j < 4; ++j) {
            short8 vv = *reinterpret_cast<short8*>(&T[ol * 144 + nbl + j * 8]);
            short8 ov;
            if (s_ & 1) ov = short8{vv[4], vv[5], vv[6], vv[7], vv[0], vv[1], vv[2], vv[3]};
            else        ov = vv;
            *reinterpret_cast<short8*>(dst + (((2 * j) ^ (s_ & 6)) * 4)) = ov;
        }
    }
}

// ---------------- Kernel 3: flash attention, 64-key staging, V in two 32-key halves ----------------
// Grid (4 sp, 4 b, 16 qtiles): XCD-local K/V slices. Block = 512 thr = 8 waves, wave owns 32 q.
__global__ __launch_bounds__(512, 1) void k_flash(const u16* __restrict__ Qw, const u16* __restrict__ Kw,
                                                  const u16* __restrict__ Vw, u16* __restrict__ Opart,
                                                  float* __restrict__ ml) {
    __shared__ u16 Ks[2][16384];    // [64 keys][256 ch], 16B-granule XOR(row&7) swizzle
    __shared__ u16 Vs[2][16384];    // two halves: [st][256 ch][32 keys], slot-swizzled
    const int sp = blockIdx.x, b = blockIdx.y;
    const int tid = threadIdx.x;
    const int w = tid >> 6, l = tid & 63;
    const int lr = l & 15, lg = l >> 4;
    const int qbase = blockIdx.z * 256 + w * 32;
    const int kb0 = sp * 1024;
    const size_t bN = (size_t)b * 4096;

    const u16* srcK = Kw + (bN + kb0 + (tid >> 5)) * 256 + (((tid & 31) * 8) ^ (((tid >> 5) & 7) * 8));
    const int u = tid & 255, sth = tid >> 8;   // V: 256-thread group per 32-key half
    const u16* srcV = Vw + ((size_t)b * 256 + (u >> 2)) * 4096 + kb0 + sth * 32 + (u & 3) * 8;
    const int vdst = sth * 8192 + u * 8;       // wave-uniform base + lane*8

#define STAGE(d, toff) { \
        const u16* sk_ = srcK + (size_t)(toff) * 16384; \
        const u16* sv_ = srcV + (toff) * 64; \
        gload16(sk_,               Ks[d] + tid * 8); \
        gload16(sk_ + 16 * 256,    Ks[d] + 4096 + tid * 8); \
        gload16(sk_ + 32 * 256,    Ks[d] + 8192 + tid * 8); \
        gload16(sk_ + 48 * 256,    Ks[d] + 12288 + tid * 8); \
        gload16(sv_,               Vs[d] + vdst); \
        gload16(sv_ + 64 * 4096,   Vs[d] + vdst + 2048); \
        gload16(sv_ + 128 * 4096,  Vs[d] + vdst + 4096); \
        gload16(sv_ + 192 * 4096,  Vs[d] + vdst + 6144); }

    const int c6 = (lr >> 2) & 1;
    int kofs[2];
#pragma unroll
    for (int n = 0; n < 2; ++n) kofs[n] = (n * 16 + lr) * 256 + ((lg * 8) ^ ((lr & 3) * 8));
    const int vslotA = ((lg ^ (lr >> 1)) * 4);   // r4-verified slot math (32-key rows)
    const int vslotB = vslotA ^ 16;

    short8 qf[2][8];
#pragma unroll
    for (int m = 0; m < 2; ++m)
#pragma unroll
        for (int cc = 0; cc < 8; ++cc)
            qf[m][cc] = *reinterpret_cast<const short8*>(&Qw[(bN + qbase + m * 16 + lr) * 256 + cc * 32 + lg * 8]);

    f32x4 Oa[2][16];
    float mr[2], lsum[2];
#pragma unroll
    for (int m = 0; m < 2; ++m) {
#pragma unroll
        for (int cs = 0; cs < 16; ++cs) Oa[m][cs] = f32x4{0.f, 0.f, 0.f, 0.f};
        mr[m] = -1e30f; lsum[m] = 0.f;
    }

    STAGE(0, 0);
    for (int kt = 0; kt < 16; ++kt) {
        const int d = kt & 1;
        asm volatile("s_waitcnt vmcnt(0)" ::: "memory");
        __builtin_amdgcn_sched_barrier(0);
        __builtin_amdgcn_s_barrier();
        if (kt < 15) STAGE(d ^ 1, kt + 1);

#pragma unroll
        for (int st = 0; st < 2; ++st) {
            const int kO = st * 8192;
            const int vH = st * 8192;           // V half base (u16)
            f32x4 sc[2][2];
#pragma unroll
            for (int m = 0; m < 2; ++m)
#pragma unroll
                for (int n = 0; n < 2; ++n) sc[m][n] = f32x4{0.f, 0.f, 0.f, 0.f};
            __builtin_amdgcn_s_setprio(1);
#pragma unroll
            for (int cc = 0; cc < 8; ++cc) {
                const int cb = ((cc ^ c6) << 5);
                short8 kf0 = *reinterpret_cast<const short8*>(&Ks[d][kO + kofs[0] + cb]);
                short8 kf1 = *reinterpret_cast<const short8*>(&Ks[d][kO + kofs[1] + cb]);
                sc[0][0] = __builtin_amdgcn_mfma_f32_16x16x32_bf16(kf0, qf[0][cc], sc[0][0], 0, 0, 0);
                sc[0][1] = __builtin_amdgcn_mfma_f32_16x16x32_bf16(kf1, qf[0][cc], sc[0][1], 0, 0, 0);
                sc[1][0] = __builtin_amdgcn_mfma_f32_16x16x32_bf16(kf0, qf[1][cc], sc[1][0], 0, 0, 0);
                sc[1][1] = __builtin_amdgcn_mfma_f32_16x16x32_bf16(kf1, qf[1][cc], sc[1][1], 0, 0, 0);
            }
            __builtin_amdgcn_s_setprio(0);

            float tmax[2];
            bool need = false;
#pragma unroll
            for (int m = 0; m < 2; ++m) {
                float tm = fmaxf(fmaxf(fmaxf(sc[m][0][0], sc[m][0][1]), fmaxf(sc[m][0][2], sc[m][0][3])),
                                 fmaxf(fmaxf(sc[m][1][0], sc[m][1][1]), fmaxf(sc[m][1][2], sc[m][1][3])));
                tm = fmaxf(tm, __shfl_xor(tm, 16));
                tm = fmaxf(tm, __shfl_xor(tm, 32));
                tmax[m] = tm;
                need = need || (tm > mr[m] + 8.f);
            }
            if (__any(need)) {   // defer-max (T13)
                float av[2][4];
#pragma unroll
                for (int m = 0; m < 2; ++m) {
                    float mn = fmaxf(mr[m], tmax[m]);
                    float al = exp2f(mr[m] - mn);
                    mr[m] = mn;
                    lsum[m] *= al;
#pragma unroll
                    for (int i = 0; i < 4; ++i) av[m][i] = __shfl(al, lg * 4 + i);
                }
#pragma unroll
                for (int m = 0; m < 2; ++m)
#pragma unroll
                    for (int cs = 0; cs < 16; ++cs)
#pragma unroll
                        for (int i = 0; i < 4; ++i) Oa[m][cs][i] *= av[m][i];
            }
            union { u32 uw[4]; short8 v; } pf[2];
#pragma unroll
            for (int m = 0; m < 2; ++m) {
                float p[8];
                float la = 0.f;
#pragma unroll
                for (int n = 0; n < 2; ++n)
#pragma unroll
                    for (int i = 0; i < 4; ++i) {
                        float pv = exp2f(sc[m][n][i] - mr[m]);
                        la += pv;
                        p[n * 4 + i] = pv;
                    }
                lsum[m] += la;
#pragma unroll
                for (int j = 0; j < 4; ++j) pf[m].uw[j] = cvtpk(p[2 * j], p[2 * j + 1]);
            }
            __builtin_amdgcn_s_setprio(1);
#pragma unroll
            for (int cs = 0; cs < 16; ++cs) {
                const int base = vH + (cs * 16 + lr) * 32;
                short4v lo = *reinterpret_cast<const short4v*>(&Vs[d][base + vslotA]);
                short4v hi = *reinterpret_cast<const short4v*>(&Vs[d][base + vslotB]);
                short8 vf = __builtin_shufflevector(lo, hi, 0, 1, 2, 3, 4, 5, 6, 7);
                Oa[0][cs] = __builtin_amdgcn_mfma_f32_16x16x32_bf16(pf[0].v, vf, Oa[0][cs], 0, 0, 0);
                Oa[1][cs] = __builtin_amdgcn_mfma_f32_16x16x32_bf16(pf[1].v, vf, Oa[1][cs], 0, 0, 0);
            }
            __builtin_amdgcn_s_setprio(0);
        }
    }
#undef STAGE

    float lt[2];
#pragma unroll
    for (int m = 0; m < 2; ++m) {
        float ts = lsum[m];
        ts += __shfl_xor(ts, 16);
        ts += __shfl_xor(ts, 32);
        lt[m] = ts;
    }
    const size_t obase = ((size_t)(b * 4 + sp) * 4096 + qbase);
#pragma unroll
    for (int m = 0; m < 2; ++m)
#pragma unroll
        for (int cs = 0; cs < 16; ++cs)
#pragma unroll
            for (int i = 0; i < 4; ++i)
                Opart[(obase + m * 16 + lg * 4 + i) * 256 + cs * 16 + lr] = f2bf(Oa[m][cs][i]);
    if (lg == 0) {
#pragma unroll
        for (int m = 0; m < 2; ++m) {
            size_t r = obase + m * 16 + lr;
            ml[r * 2]     = mr[m];
            ml[r * 2 + 1] = lt[m];
        }
    }
}

// ---------------- Kernel 3b: combine split-KV partials -> Obf (B,N,C) bf16 ----------------
__global__ __launch_bounds__(256) void k_comb(const u16* __restrict__ Opart, const float* __restrict__ ml,
                                              u16* __restrict__ Obf) {
    const int row = blockIdx.x * 8 + (threadIdx.x >> 5);   // b*4096 + n
    const int b = row >> 12;
    const int c0 = (threadIdx.x & 31) * 8;
    const size_t rbase = (size_t)b * 4 * 4096 + (row & 4095);
    float ms[4], lsv[4];
#pragma unroll
    for (int s = 0; s < 4; ++s) {
        ms[s]  = ml[(rbase + (size_t)s * 4096) * 2];
        lsv[s] = ml[(rbase + (size_t)s * 4096) * 2 + 1];
    }
    float M = fmaxf(fmaxf(ms[0], ms[1]), fmaxf(ms[2], ms[3]));
    float W[4], L = 0.f;
#pragma unroll
    for (int s = 0; s < 4; ++s) { W[s] = exp2f(ms[s] - M); L += W[s] * lsv[s]; }
    const float inv = 1.f / L;
    float o[8] = {};
#pragma unroll
    for (int s = 0; s < 4; ++s) {
        short8 v = *reinterpret_cast<const short8*>(&Opart[(rbase + (size_t)s * 4096) * 256 + c0]);
#pragma unroll
        for (int j = 0; j < 8; ++j) o[j] += W[s] * bf2f((u16)v[j]);
    }
    short8 r;
#pragma unroll
    for (int j = 0; j < 8; ++j) r[j] = (short)f2bf(o[j] * inv);
    *reinterpret_cast<short8*>(&Obf[(size_t)row * 256 + c0]) = r;
}

// ---------------- Kernel 4: proj as bf16 MFMA GEMM + bias + residual ----------------
__global__ __launch_bounds__(256) void k_proj(const u16* __restrict__ O, const u16* __restrict__ Wp,
                                              const float* __restrict__ proj_b, const float* __restrict__ x,
                                              float* __restrict__ out) {
    __shared__ float T[64][132];   // [c_local][n_local] f32
    const int b = blockIdx.z, c0 = blockIdx.x * 64, nb0 = blockIdx.y * 128;
    const int t = threadIdx.x, w = t >> 6, l = t & 63, lr = l & 15, lg = l >> 4;
    const size_t bN = (size_t)b * 4096;
    f32x4 acc[2][4];
#pragma unroll
    for (int m = 0; m < 2; ++m)
#pragma unroll
        for (int nf = 0; nf < 4; ++nf) acc[m][nf] = f32x4{0.f, 0.f, 0.f, 0.f};
    const u16* A0 = &O[(bN + nb0 + w * 32 + lr) * 256];
    const u16* A1 = A0 + 16 * 256;
#pragma unroll
    for (int cc = 0; cc < 8; ++cc) {
        short8 af0 = *reinterpret_cast<const short8*>(A0 + cc * 32 + lg * 8);
        short8 af1 = *reinterpret_cast<const short8*>(A1 + cc * 32 + lg * 8);
#pragma unroll
        for (int nf = 0; nf < 4; ++nf) {
            short8 bf = *reinterpret_cast<const short8*>(&Wp[(size_t)(c0 + nf * 16 + lr) * 256 + cc * 32 + lg * 8]);
            acc[0][nf] = __builtin_amdgcn_mfma_f32_16x16x32_bf16(af0, bf, acc[0][nf], 0, 0, 0);
            acc[1][nf] = __builtin_amdgcn_mfma_f32_16x16x32_bf16(af1, bf, acc[1][nf], 0, 0, 0);
        }
    }
#pragma unroll
    for (int m = 0; m < 2; ++m)
#pragma unroll
        for (int nf = 0; nf < 4; ++nf)
#pragma unroll
            for (int i = 0; i < 4; ++i)
                T[nf * 16 + lr][w * 32 + m * 16 + lg * 4 + i] = acc[m][nf][i];
    __syncthreads();
    const int cl = t >> 2, nbl = (t & 3) * 32;
    const float pb = proj_b[c0 + cl];
    const size_t base = ((size_t)b * 256 + c0 + cl) * 4096 + nb0 + nbl;
#pragma unroll
    for (int j = 0; j < 32; j += 4) {
        float4 xv = *reinterpret_cast<const float4*>(&x[base + j]);
        float4 r;
        r.x = xv.x + T[cl][nbl + j + 0] + pb;
        r.y = xv.y + T[cl][nbl + j + 1] + pb;
        r.z = xv.z + T[cl][nbl + j + 2] + pb;
        r.w = xv.w + T[cl][nbl + j + 3] + pb;
        *reinterpret_cast<float4*>(&out[base + j]) = r;
    }
}

extern "C" void kernel_launch(void* const* d_in, const int* in_sizes, int n_in,
                              void* d_out, int out_size, void* d_ws, size_t ws_size,
                              hipStream_t stream) {
    const float* x      = (const float*)d_in[0];
    const float* gngam  = (const float*)d_in[1];
    const float* gnbeta = (const float*)d_in[2];
    const float* qkv_w  = (const float*)d_in[3];
    const float* qkv_b  = (const float*)d_in[4];
    const float* proj_w = (const float*)d_in[5];
    const float* proj_b = (const float*)d_in[6];
    float* out = (float*)d_out;

    char* wsb = (char*)d_ws;
    float* pstats = (float*)wsb;                      // 2 KB (32 groups x 8 slices x 2)
    u16* Hbf   = (u16*)(wsb + 4096);                  // 8 MB (B,N,C)
    u16* Qws   = Hbf + 4194304;                       // 8 MB (B,N,C) pre-scaled
    u16* Kws   = Qws + 4194304;                       // 8 MB (B,N,C)
    u16* Vws   = Kws + 4194304;                       // 8 MB (B,C,N) slot-swizzled
    u16* W2q   = Vws + 4194304;                       // 384 KB
    u16* W2p   = W2q + 196608;                        // 128 KB
    u16* Opart = W2p + 65536;                         // 32 MB (B,S,N,C) unnormalized
    float* ml  = (float*)(Opart + 16777216);          // 512 KB (B,S,N,2)
    u16* Obf   = (u16*)(ml + 131072);                 // 8 MB (B,N,C)

    k_pre<<<512, 256, 0, stream>>>(x, pstats, qkv_w, proj_w, W2q, W2p);
    k_norm<<<dim3(64, 4, 4), 256, 0, stream>>>(x, gngam, gnbeta, pstats, Hbf);
    k_qkv<<<dim3(12, 32, 4), 256, 0, stream>>>(Hbf, W2q, qkv_b, Qws, Kws, Vws);
    k_flash<<<dim3(4, 4, 16), 512, 0, stream>>>(Qws, Kws, Vws, Opart, ml);
    k_comb<<<2048, 256, 0, stream>>>(Opart, ml, Obf);
    k_proj<<<dim3(4, 32, 4), 256, 0, stream>>>(Obf, W2p, proj_b, x, out);
}